// Round 4
// baseline (531.970 us; speedup 1.0000x reference)
//
#include <hip/hip_runtime.h>
#include <hip/hip_bf16.h>

// GraphVertEdgeNet on MI355X. B=64, N=64, VF=32, EF=16, DV=DE=128, LN=4.
// e stored bf16 in ws (64MB). Edge kernels: MFMA D[c][i] orientation,
// ev_i+ev_j+eb folded into C-init, residual via LDS. v-pass (concat matmul
// + residual + BN stats) fused into edge kernel epilogue (pve is in-block
// complete). 13 dispatches total.

typedef __bf16 bf16_t;
typedef __bf16 bf16x8 __attribute__((ext_vector_type(8)));
typedef __bf16 bf16x4 __attribute__((ext_vector_type(4)));
typedef float f32x4 __attribute__((ext_vector_type(4)));

// ---------------- prep: input BN (v0), Wt transpose, zero pve3/stats ----------------
__global__ __launch_bounds__(256) void k_prep(const float* __restrict__ vin,
    const float* __restrict__ g, const float* __restrict__ bt,
    const float* __restrict__ eW, float* __restrict__ v0,
    bf16_t* __restrict__ Wt, float* __restrict__ pve3, float* __restrict__ stats) {
  const int blk = blockIdx.x, tid = threadIdx.x;
  if (blk < 8) {  // BatchNorm1d(N*VF) over batch, ch = 0..2047
    int ch = blk * 256 + tid;
    float s = 0.f, s2 = 0.f;
    for (int b = 0; b < 64; ++b) { float x = vin[b * 2048 + ch]; s += x; s2 += x * x; }
    float mu = s * (1.f / 64.f);
    float var = s2 * (1.f / 64.f) - mu * mu;  // biased var
    float sc = rsqrtf(var + 1e-5f) * g[ch];
    float bb = bt[ch];
    for (int b = 0; b < 64; ++b) {
      float x = vin[b * 2048 + ch];
      v0[b * 2048 + ch] = (x - mu) * sc + bb;
    }
  } else if (blk < 264) {  // Wt[l][n][k] = eW[l][k][n] as bf16
    int idx = (blk - 8) * 256 + tid;  // 4*128*128 = 65536
    int l = idx >> 14, r = idx & 16383, n = r >> 7, k = r & 127;
    Wt[idx] = (bf16_t)eW[(l << 14) + (k << 7) + n];
  } else {  // zero pve3 (4096 f32) + stats (512 f32)
    for (int i = tid; i < 4096; i += 256) pve3[i] = 0.f;
    for (int i = tid; i < 512; i += 256) stats[i] = 0.f;
  }
}

// ------------- ev = v_in @ W + bias : [4096,K] @ [K,128] -> [4096,128] -------------
template <int K>
__global__ __launch_bounds__(128) void k_ev(const float* __restrict__ v_in,
    const float* __restrict__ W, const float* __restrict__ bias,
    float* __restrict__ out) {
  __shared__ float rows[8][K];
  const int r0 = blockIdx.x * 8;
  const int c = threadIdx.x;  // 128 threads
  for (int idx = c; idx < 8 * K; idx += 128) {
    int rr = idx / K, kk = idx % K;
    rows[rr][kk] = v_in[(r0 + rr) * K + kk];
  }
  __syncthreads();
  float acc[8];
  const float bv = bias[c];
#pragma unroll
  for (int r = 0; r < 8; ++r) acc[r] = bv;
  for (int k4 = 0; k4 < K; k4 += 4) {
    float w0 = W[(k4 + 0) * 128 + c], w1 = W[(k4 + 1) * 128 + c];
    float w2 = W[(k4 + 2) * 128 + c], w3 = W[(k4 + 3) * 128 + c];
#pragma unroll
    for (int r = 0; r < 8; ++r) {
      float4 x = *(const float4*)&rows[r][k4];
      acc[r] += x.x * w0 + x.y * w1 + x.z * w2 + x.w * w3;
    }
  }
#pragma unroll
  for (int r = 0; r < 8; ++r) out[(r0 + r) * 128 + c] = acc[r];
}

// ------------- fused BN(prev layer) + ev matmul: normalizes v in place -------------
__global__ __launch_bounds__(128) void k_evbn(float* __restrict__ v,
    const float* __restrict__ stats, const float* __restrict__ g,
    const float* __restrict__ bt, const float* __restrict__ W,
    const float* __restrict__ bias, float* __restrict__ out) {
  __shared__ float rows[8][128];
  const int r0 = blockIdx.x * 8;
  const int c = threadIdx.x;
#pragma unroll
  for (int rr = 0; rr < 8; ++rr) {
    int n = (r0 + rr) & 63;
    float mu = stats[n] * (1.f / 8192.f);
    float var = stats[64 + n] * (1.f / 8192.f) - mu * mu;
    float sc = rsqrtf(var + 128.f) * g[n];
    float x = (v[(r0 + rr) * 128 + c] - mu) * sc + bt[n];
    rows[rr][c] = x;
    v[(r0 + rr) * 128 + c] = x;  // normalized v for edge kernel's residual
  }
  __syncthreads();
  float acc[8];
  const float bv = bias[c];
#pragma unroll
  for (int r = 0; r < 8; ++r) acc[r] = bv;
  for (int k4 = 0; k4 < 128; k4 += 4) {
    float w0 = W[(k4 + 0) * 128 + c], w1 = W[(k4 + 1) * 128 + c];
    float w2 = W[(k4 + 2) * 128 + c], w3 = W[(k4 + 3) * 128 + c];
#pragma unroll
    for (int r = 0; r < 8; ++r) {
      float4 x = *(const float4*)&rows[r][k4];
      acc[r] += x.x * w0 + x.y * w1 + x.z * w2 + x.w * w3;
    }
  }
#pragma unroll
  for (int r = 0; r < 8; ++r) out[(r0 + r) * 128 + c] = acc[r];
}

// ------------- g1 edge pass (MFMA, K 16->32 zero-pad, 2 j/block) + fused v_g1 -------------
__global__ __launch_bounds__(256) void k_edge_g1(const float* __restrict__ e0,
    const float* __restrict__ eW, const float* __restrict__ eb,
    const float* __restrict__ ev, const float* __restrict__ v0,
    const float* __restrict__ vW, const float* __restrict__ vb,
    bf16_t* __restrict__ e_ws, float* __restrict__ v) {
  __shared__ bf16_t A0s[2][64][40];
  __shared__ bf16_t Os[2][64][136];
  __shared__ float vr0[2][32];
  __shared__ float pves[2][128];
  const int b = blockIdx.x >> 5, j0 = (blockIdx.x & 31) * 2;
  const int tid = threadIdx.x;
  const int lane = tid & 63, w = tid >> 6;
  const int quad = lane >> 4, l16 = lane & 15;
  // stage e0 two columns -> bf16, zero-pad K 16..31
#pragma unroll
  for (int t = 0; t < 2; ++t) {
    int idx = tid + t * 256;
    int row = idx >> 3, off = (idx & 7) * 4;  // off in floats 0..31
    int jc = off >> 4, k = off & 15;
    f32x4 x = *(const f32x4*)&e0[((b * 64 + row) * 64 + j0) * 16 + off];
    bf16x4 y;
#pragma unroll
    for (int r = 0; r < 4; ++r) y[r] = (bf16_t)x[r];
    *(bf16x4*)&A0s[jc][row][k] = y;
    bf16x4 z = {(bf16_t)0.f, (bf16_t)0.f, (bf16_t)0.f, (bf16_t)0.f};
    *(bf16x4*)&A0s[jc][row][16 + k] = z;
  }
  if (tid < 64) vr0[tid >> 5][tid & 31] = v0[(b * 64 + j0 + (tid >> 5)) * 32 + (tid & 31)];
  const int c0[2] = {w * 32 + quad * 4, w * 32 + 16 + quad * 4};
  // W A-frags: A[m=c][k=quad*8+jj], zero for k>=16
  bf16x8 wf[2];
#pragma unroll
  for (int nt = 0; nt < 2; ++nt) {
    const int c = w * 32 + nt * 16 + l16;
#pragma unroll
    for (int jj = 0; jj < 8; ++jj)
      wf[nt][jj] = (quad < 2) ? (bf16_t)eW[(quad * 8 + jj) * 128 + c] : (bf16_t)0.f;
  }
  // acc init = eb + ev_j + ev_i
  f32x4 acc[2][4][2];
  {
    f32x4 ebv[2], evj[2][2], evi[4][2];
#pragma unroll
    for (int nt = 0; nt < 2; ++nt) {
      ebv[nt] = *(const f32x4*)&eb[c0[nt]];
#pragma unroll
      for (int jc = 0; jc < 2; ++jc)
        evj[jc][nt] = *(const f32x4*)&ev[(b * 64 + j0 + jc) * 128 + c0[nt]];
#pragma unroll
      for (int mt = 0; mt < 4; ++mt)
        evi[mt][nt] = *(const f32x4*)&ev[(b * 64 + mt * 16 + l16) * 128 + c0[nt]];
    }
#pragma unroll
    for (int jc = 0; jc < 2; ++jc)
#pragma unroll
      for (int mt = 0; mt < 4; ++mt)
#pragma unroll
        for (int nt = 0; nt < 2; ++nt)
          acc[jc][mt][nt] = ebv[nt] + evj[jc][nt] + evi[mt][nt];
  }
  __syncthreads();
#pragma unroll
  for (int jc = 0; jc < 2; ++jc) {
#pragma unroll
    for (int mt = 0; mt < 4; ++mt) {
      bf16x8 ef = *(const bf16x8*)&A0s[jc][mt * 16 + l16][quad * 8];
#pragma unroll
      for (int nt = 0; nt < 2; ++nt)
        acc[jc][mt][nt] = __builtin_amdgcn_mfma_f32_16x16x32_bf16(wf[nt], ef, acc[jc][mt][nt], 0, 0, 0);
    }
  }
  // epilogue: relu, pve -> LDS, pack to Os
#pragma unroll
  for (int jc = 0; jc < 2; ++jc) {
#pragma unroll
    for (int nt = 0; nt < 2; ++nt) {
      f32x4 ps = {0.f, 0.f, 0.f, 0.f};
#pragma unroll
      for (int mt = 0; mt < 4; ++mt) {
        const int i = mt * 16 + l16;
        bf16x4 outv;
#pragma unroll
        for (int r = 0; r < 4; ++r) {
          float vv = fmaxf(acc[jc][mt][nt][r], 0.f);
          ps[r] += vv;
          outv[r] = (bf16_t)vv;
        }
        *(bf16x4*)&Os[jc][i][c0[nt]] = outv;
      }
#pragma unroll
      for (int m = 1; m <= 8; m <<= 1) {
#pragma unroll
        for (int r = 0; r < 4; ++r) ps[r] += __shfl_xor(ps[r], m);
      }
      if (l16 == 0) *(f32x4*)&pves[jc][c0[nt]] = ps;
    }
  }
  __syncthreads();
#pragma unroll
  for (int t = 0; t < 8; ++t) {  // coalesced e copy-out: 512B per row (2 cols)
    int idx = tid + t * 256;
    int row = idx >> 5, off = (idx & 31) * 8;
    int jc = off >> 7, c = off & 127;
    *(int4*)&e_ws[((b * 64 + row) * 64 + j0) * 128 + off] = *(const int4*)&Os[jc][row][c];
  }
  // fused v_g1: v[b,j0+jc,:] = relu(concat(pve, v0row) @ vW[160][128] + vb)
  {
    const int jc = tid >> 7, c = tid & 127;
    float a = vb[c];
    for (int k = 0; k < 128; ++k) a += pves[jc][k] * vW[k * 128 + c];
#pragma unroll
    for (int k = 0; k < 32; ++k) a += vr0[jc][k] * vW[(128 + k) * 128 + c];
    v[(b * 64 + j0 + jc) * 128 + c] = fmaxf(a, 0.f);
  }
}

// ------------- inner edge pass (MFMA, D[c][i], 2 j/block) + fused v-pass + BN stats -------------
__global__ __launch_bounds__(256) void k_edge_inner(bf16_t* __restrict__ e_ws,
    const bf16_t* __restrict__ Wt, const float* __restrict__ eb,
    const float* __restrict__ ev, float* __restrict__ v,
    const float* __restrict__ vW, const float* __restrict__ vb,
    float* __restrict__ stats) {
  __shared__ bf16_t As[2][64][136];   // +8 pad per row
  __shared__ float vrow[2][128];
  __shared__ float pves[2][128];
  const int b = blockIdx.x >> 5, j0 = (blockIdx.x & 31) * 2;
  const int tid = threadIdx.x;
  const int lane = tid & 63, w = tid >> 6;
  const int quad = lane >> 4, l16 = lane & 15;
  // stage 2 e columns: 512B contiguous per row
  int4 stg[8];
#pragma unroll
  for (int t = 0; t < 8; ++t) {
    int idx = tid + t * 256;
    int row = idx >> 5, off = (idx & 31) * 8;
    stg[t] = *(const int4*)&e_ws[((b * 64 + row) * 64 + j0) * 128 + off];
  }
  if (tid < 256) vrow[tid >> 7][tid & 127] = v[(b * 64 + j0 + (tid >> 7)) * 128 + (tid & 127)];
  // W A-frags in registers (L2-hot): A[m=c][k]
  bf16x8 wf[2][4];
#pragma unroll
  for (int nt = 0; nt < 2; ++nt)
#pragma unroll
    for (int ks = 0; ks < 4; ++ks)
      wf[nt][ks] = *(const bf16x8*)&Wt[(w * 32 + nt * 16 + l16) * 128 + ks * 32 + quad * 8];
  const int c0[2] = {w * 32 + quad * 4, w * 32 + 16 + quad * 4};
  // acc init = eb + ev_j + ev_i (pre-barrier loads)
  f32x4 acc[2][4][2];
  {
    f32x4 ebv[2], evj[2][2], evi[4][2];
#pragma unroll
    for (int nt = 0; nt < 2; ++nt) {
      ebv[nt] = *(const f32x4*)&eb[c0[nt]];
#pragma unroll
      for (int jc = 0; jc < 2; ++jc)
        evj[jc][nt] = *(const f32x4*)&ev[(b * 64 + j0 + jc) * 128 + c0[nt]];
#pragma unroll
      for (int mt = 0; mt < 4; ++mt)
        evi[mt][nt] = *(const f32x4*)&ev[(b * 64 + mt * 16 + l16) * 128 + c0[nt]];
    }
#pragma unroll
    for (int jc = 0; jc < 2; ++jc)
#pragma unroll
      for (int mt = 0; mt < 4; ++mt)
#pragma unroll
        for (int nt = 0; nt < 2; ++nt)
          acc[jc][mt][nt] = ebv[nt] + evj[jc][nt] + evi[mt][nt];
  }
#pragma unroll
  for (int t = 0; t < 8; ++t) {
    int idx = tid + t * 256;
    int row = idx >> 5, off = (idx & 31) * 8;
    *(int4*)&As[off >> 7][row][off & 127] = stg[t];
  }
  __syncthreads();
  // MFMA: D[c][i] = sum_k Wt[c][k] * e[i][k]  (64 MFMA per wave)
#pragma unroll
  for (int ks = 0; ks < 4; ++ks) {
    bf16x8 ef[2][4];
#pragma unroll
    for (int jc = 0; jc < 2; ++jc)
#pragma unroll
      for (int mt = 0; mt < 4; ++mt)
        ef[jc][mt] = *(const bf16x8*)&As[jc][mt * 16 + l16][ks * 32 + quad * 8];
#pragma unroll
    for (int jc = 0; jc < 2; ++jc)
#pragma unroll
      for (int mt = 0; mt < 4; ++mt)
#pragma unroll
        for (int nt = 0; nt < 2; ++nt)
          acc[jc][mt][nt] = __builtin_amdgcn_mfma_f32_16x16x32_bf16(wf[nt][ks], ef[jc][mt], acc[jc][mt][nt], 0, 0, 0);
  }
  __syncthreads();  // all As reads done before in-place update
  // epilogue: relu, pve, residual from LDS, packed b64 writes
#pragma unroll
  for (int jc = 0; jc < 2; ++jc) {
#pragma unroll
    for (int nt = 0; nt < 2; ++nt) {
      f32x4 ps = {0.f, 0.f, 0.f, 0.f};
#pragma unroll
      for (int mt = 0; mt < 4; ++mt) {
        const int i = mt * 16 + l16;
        bf16x4 eo = *(const bf16x4*)&As[jc][i][c0[nt]];
        bf16x4 outv;
#pragma unroll
        for (int r = 0; r < 4; ++r) {
          float vv = fmaxf(acc[jc][mt][nt][r], 0.f);
          ps[r] += vv;                            // pve is pre-residual
          outv[r] = (bf16_t)(vv + (float)eo[r]);  // residual
        }
        *(bf16x4*)&As[jc][i][c0[nt]] = outv;
      }
#pragma unroll
      for (int m = 1; m <= 8; m <<= 1) {  // reduce over i (l16 lanes)
#pragma unroll
        for (int r = 0; r < 4; ++r) ps[r] += __shfl_xor(ps[r], m);
      }
      if (l16 == 0) *(f32x4*)&pves[jc][c0[nt]] = ps;
    }
  }
  __syncthreads();
#pragma unroll
  for (int t = 0; t < 8; ++t) {  // coalesced e write-back: 512B per row
    int idx = tid + t * 256;
    int row = idx >> 5, off = (idx & 31) * 8;
    *(int4*)&e_ws[((b * 64 + row) * 64 + j0) * 128 + off] = *(const int4*)&As[off >> 7][row][off & 127];
  }
  // fused v-pass: v_next = relu(concat(pve, v) @ vW[256][128] + vb) + v, + BN stats
  {
    const int jc = tid >> 7, c = tid & 127;
    float a = vb[c];
    for (int k = 0; k < 128; ++k) a += pves[jc][k] * vW[k * 128 + c];
    for (int k = 0; k < 128; ++k) a += vrow[jc][k] * vW[(128 + k) * 128 + c];
    float val = fmaxf(a, 0.f) + vrow[jc][c];
    v[(b * 64 + j0 + jc) * 128 + c] = val;
    // BN stats over (B,D) per channel n=j0+jc: wave-level reduce + 2 atomics
    float s = val, s2 = val * val;
#pragma unroll
    for (int m = 1; m < 64; m <<= 1) {
      s += __shfl_xor(s, m);
      s2 += __shfl_xor(s2, m);
    }
    if (lane == 0) {
      atomicAdd(&stats[j0 + jc], s);
      atomicAdd(&stats[64 + j0 + jc], s2);
    }
  }
}

// ------------- g3 edge (fused BN + ev3): e3 = e.W3 + eb + ev3_i + ev3_j -------------
__global__ __launch_bounds__(256) void k_edge_g3(const bf16_t* __restrict__ e_ws,
    const float* __restrict__ vv, const float* __restrict__ stats3,
    const float* __restrict__ g, const float* __restrict__ bt,
    const float* __restrict__ evW3, const float* __restrict__ evb3,
    const float* __restrict__ eW3, const float* __restrict__ eb3,
    float* __restrict__ out_e, float* __restrict__ pve3) {
  __shared__ float vbn[64][132];  // +4 pad
  __shared__ float scs[64], shs[64];
  __shared__ float W3e[128], W3ee[128];
  __shared__ float ev3s[64];
  const int b = blockIdx.x >> 6, i = blockIdx.x & 63;
  const int tid = threadIdx.x;
  if (tid < 64) {
    float mu = stats3[tid] * (1.f / 8192.f);
    float var = stats3[64 + tid] * (1.f / 8192.f) - mu * mu;
    float sc = rsqrtf(var + 128.f) * g[tid];
    scs[tid] = sc;
    shs[tid] = bt[tid] - mu * sc;
  }
  if (tid < 128) W3ee[tid] = eW3[tid];
  else W3e[tid - 128] = evW3[tid - 128];
  __syncthreads();
  // BN-stage v[b] (all 64 rows)
#pragma unroll
  for (int t = 0; t < 8; ++t) {
    int idx = t * 1024 + tid * 4;
    int row = idx >> 7, c = idx & 127;
    f32x4 x = *(const f32x4*)&vv[(b * 64 + row) * 128 + c];
    f32x4 y = x * scs[row] + shs[row];
    *(f32x4*)&vbn[row][c] = y;
  }
  __syncthreads();
  // ev3[r] = dot(vbn[r], W3e) + evb3
  {
    int r = tid >> 2, q = tid & 3;
    float a = 0.f;
#pragma unroll
    for (int u = 0; u < 32; ++u) a += vbn[r][q * 32 + u] * W3e[q * 32 + u];
    a += __shfl_xor(a, 1);
    a += __shfl_xor(a, 2);
    if (q == 0) ev3s[r] = a + evb3[0];
  }
  __syncthreads();
  // e3 row: 4 threads per j
  {
    const int j = tid >> 2, cs = (tid & 3) * 32;
    const bf16_t* ep = &e_ws[(size_t)((b * 64 + i) * 64 + j) * 128 + cs];
    float acc = 0.f;
#pragma unroll
    for (int t = 0; t < 4; ++t) {
      bf16x8 x = *(const bf16x8*)&ep[t * 8];
#pragma unroll
      for (int u = 0; u < 8; ++u) acc += (float)x[u] * W3ee[cs + t * 8 + u];
    }
    acc += __shfl_xor(acc, 1);
    acc += __shfl_xor(acc, 2);
    if ((tid & 3) == 0) {
      float s = acc + eb3[0] + ev3s[i] + ev3s[j];
      out_e[(b * 64 + i) * 64 + j] = s;
      atomicAdd(&pve3[b * 64 + j], s);
    }
  }
}

// ------------- g3 v (fused BN): v3 = pve3*W[0] + vbn.W[1:] + b -------------
__global__ __launch_bounds__(256) void k_v_g3(const float* __restrict__ vv,
    const float* __restrict__ stats3, const float* __restrict__ g,
    const float* __restrict__ bt, const float* __restrict__ pve3,
    const float* __restrict__ vW, const float* __restrict__ vb,
    float* __restrict__ out_v) {
  int r = blockIdx.x * 4 + (threadIdx.x >> 6);
  int lane = threadIdx.x & 63;
  int n = r & 63;
  float mu = stats3[n] * (1.f / 8192.f);
  float var = stats3[64 + n] * (1.f / 8192.f) - mu * mu;
  float sc = rsqrtf(var + 128.f) * g[n];
  float sh = bt[n] - mu * sc;
  float x1 = vv[r * 128 + lane] * sc + sh;
  float x2 = vv[r * 128 + 64 + lane] * sc + sh;
  float acc = x1 * vW[1 + lane] + x2 * vW[65 + lane];
#pragma unroll
  for (int m = 1; m < 64; m <<= 1) acc += __shfl_xor(acc, m);
  if (lane == 0) out_v[r] = acc + pve3[r] * vW[0] + vb[0];
}

extern "C" void kernel_launch(void* const* d_in, const int* in_sizes, int n_in,
                              void* d_out, int out_size, void* d_ws, size_t ws_size,
                              hipStream_t stream) {
  const float* in_v    = (const float*)d_in[0];
  const float* in_e    = (const float*)d_in[1];
  const float* bn_in_g = (const float*)d_in[2];
  const float* bn_in_b = (const float*)d_in[3];
  const float* g1_evW  = (const float*)d_in[4];
  const float* g1_evb  = (const float*)d_in[5];
  const float* g1_eW   = (const float*)d_in[6];
  const float* g1_eb   = (const float*)d_in[7];
  const float* g1_vW   = (const float*)d_in[8];
  const float* g1_vb   = (const float*)d_in[9];
  const float* inn_evW = (const float*)d_in[10];
  const float* inn_evb = (const float*)d_in[11];
  const float* inn_eW  = (const float*)d_in[12];
  const float* inn_eb  = (const float*)d_in[13];
  const float* inn_vW  = (const float*)d_in[14];
  const float* inn_vb  = (const float*)d_in[15];
  const float* bn_g    = (const float*)d_in[16];
  const float* bn_b    = (const float*)d_in[17];
  const float* g3_evW  = (const float*)d_in[18];
  const float* g3_evb  = (const float*)d_in[19];
  const float* g3_eW   = (const float*)d_in[20];
  const float* g3_eb   = (const float*)d_in[21];
  const float* g3_vW   = (const float*)d_in[22];
  const float* g3_vb   = (const float*)d_in[23];

  char* ws = (char*)d_ws;
  bf16_t* e_ws = (bf16_t*)(ws);                       // 64MB : e as bf16
  float* v     = (float*)(ws + 67108864);             // 2MB
  float* ev    = (float*)(ws + 69206016);             // 2MB
  float* v0    = (float*)(ws + 73400320);             // 512KB
  bf16_t* Wt   = (bf16_t*)(ws + 73924608);            // 128KB
  float* pve3  = (float*)(ws + 74072064);             // 16KB
  float* stats = (float*)(ws + 74088448);             // 2KB (4 layers x 128 f32)

  float* out_v = (float*)d_out;          // [B,N,1] = 4096
  float* out_e = (float*)d_out + 4096;   // [B,N,N,1] = 262144

  k_prep<<<265, 256, 0, stream>>>(in_v, bn_in_g, bn_in_b, inn_eW, v0, Wt, pve3, stats);

  // ---- g1 ----
  k_ev<32><<<512, 128, 0, stream>>>(v0, g1_evW, g1_evb, ev);
  k_edge_g1<<<2048, 256, 0, stream>>>(in_e, g1_eW, g1_eb, ev, v0, g1_vW, g1_vb, e_ws, v);

  // ---- inner layers ----
  for (int l = 0; l < 4; ++l) {
    if (l == 0)
      k_ev<128><<<512, 128, 0, stream>>>(v, inn_evW, inn_evb, ev);
    else
      k_evbn<<<512, 128, 0, stream>>>(v, stats + (l - 1) * 128, bn_g + (l - 1) * 64,
                                      bn_b + (l - 1) * 64, inn_evW + l * 16384,
                                      inn_evb + l * 128, ev);
    k_edge_inner<<<2048, 256, 0, stream>>>(e_ws, Wt + l * 16384, inn_eb + l * 128, ev,
                                           v, inn_vW + l * 32768, inn_vb + l * 128,
                                           stats + l * 128);
  }

  // ---- g3 (BN of layer 3 applied on the fly) ----
  k_edge_g3<<<4096, 256, 0, stream>>>(e_ws, v, stats + 384, bn_g + 192, bn_b + 192,
                                      g3_evW, g3_evb, g3_eW, g3_eb, out_e, pve3);
  k_v_g3<<<1024, 256, 0, stream>>>(v, stats + 384, bn_g + 192, bn_b + 192, pve3,
                                   g3_vW, g3_vb, out_v);
}

// Round 5
// 457.092 us; speedup vs baseline: 1.1638x; 1.1638x over previous
//
#include <hip/hip_runtime.h>
#include <hip/hip_bf16.h>

// GraphVertEdgeNet on MI355X. B=64, N=64, VF=32, EF=16, DV=DE=128, LN=4.
// e stored bf16 in ws (64MB). Inner edge kernel: persistent blocks (4 j-tiles
// each), double-buffered LDS, lgkmcnt-only barriers (global prefetch stays in
// flight across the whole pipeline), weights/ev_i register-resident per block.
// v-pass kept as separate kernel (R4 fusion regressed: VGPR/occupancy).

typedef __bf16 bf16_t;
typedef __bf16 bf16x8 __attribute__((ext_vector_type(8)));
typedef __bf16 bf16x4 __attribute__((ext_vector_type(4)));
typedef float f32x4 __attribute__((ext_vector_type(4)));

// Barrier that does NOT drain vmcnt: safe when cross-thread deps are LDS-only.
__device__ __forceinline__ void bar_lgkm() {
  asm volatile("s_waitcnt lgkmcnt(0)\n\ts_barrier" ::: "memory");
}

// ---------------- prep: input BN (v0), Wt transpose, zero pve3/stats ----------------
__global__ __launch_bounds__(256) void k_prep(const float* __restrict__ vin,
    const float* __restrict__ g, const float* __restrict__ bt,
    const float* __restrict__ eW, float* __restrict__ v0,
    bf16_t* __restrict__ Wt, float* __restrict__ pve3, float* __restrict__ stats) {
  const int blk = blockIdx.x, tid = threadIdx.x;
  if (blk < 8) {  // BatchNorm1d(N*VF) over batch, ch = 0..2047
    int ch = blk * 256 + tid;
    float s = 0.f, s2 = 0.f;
    for (int b = 0; b < 64; ++b) { float x = vin[b * 2048 + ch]; s += x; s2 += x * x; }
    float mu = s * (1.f / 64.f);
    float var = s2 * (1.f / 64.f) - mu * mu;  // biased var
    float sc = rsqrtf(var + 1e-5f) * g[ch];
    float bb = bt[ch];
    for (int b = 0; b < 64; ++b) {
      float x = vin[b * 2048 + ch];
      v0[b * 2048 + ch] = (x - mu) * sc + bb;
    }
  } else if (blk < 264) {  // Wt[l][n][k] = eW[l][k][n] as bf16
    int idx = (blk - 8) * 256 + tid;  // 4*128*128 = 65536
    int l = idx >> 14, r = idx & 16383, n = r >> 7, k = r & 127;
    Wt[idx] = (bf16_t)eW[(l << 14) + (k << 7) + n];
  } else {  // zero pve3 (4096 f32) + stats (512 f32)
    for (int i = tid; i < 4096; i += 256) pve3[i] = 0.f;
    for (int i = tid; i < 512; i += 256) stats[i] = 0.f;
  }
}

// ------------- ev = v_in @ W + bias : [4096,K] @ [K,128] -> [4096,128] -------------
template <int K>
__global__ __launch_bounds__(128) void k_ev(const float* __restrict__ v_in,
    const float* __restrict__ W, const float* __restrict__ bias,
    float* __restrict__ out) {
  __shared__ float rows[8][K];
  const int r0 = blockIdx.x * 8;
  const int c = threadIdx.x;  // 128 threads
  for (int idx = c; idx < 8 * K; idx += 128) {
    int rr = idx / K, kk = idx % K;
    rows[rr][kk] = v_in[(r0 + rr) * K + kk];
  }
  __syncthreads();
  float acc[8];
  const float bv = bias[c];
#pragma unroll
  for (int r = 0; r < 8; ++r) acc[r] = bv;
  for (int k4 = 0; k4 < K; k4 += 4) {
    float w0 = W[(k4 + 0) * 128 + c], w1 = W[(k4 + 1) * 128 + c];
    float w2 = W[(k4 + 2) * 128 + c], w3 = W[(k4 + 3) * 128 + c];
#pragma unroll
    for (int r = 0; r < 8; ++r) {
      float4 x = *(const float4*)&rows[r][k4];
      acc[r] += x.x * w0 + x.y * w1 + x.z * w2 + x.w * w3;
    }
  }
#pragma unroll
  for (int r = 0; r < 8; ++r) out[(r0 + r) * 128 + c] = acc[r];
}

// ------------- fused BN(prev layer) + ev matmul: normalizes v in place -------------
__global__ __launch_bounds__(128) void k_evbn(float* __restrict__ v,
    const float* __restrict__ stats, const float* __restrict__ g,
    const float* __restrict__ bt, const float* __restrict__ W,
    const float* __restrict__ bias, float* __restrict__ out) {
  __shared__ float rows[8][128];
  const int r0 = blockIdx.x * 8;
  const int c = threadIdx.x;
#pragma unroll
  for (int rr = 0; rr < 8; ++rr) {
    int n = (r0 + rr) & 63;
    float mu = stats[n] * (1.f / 8192.f);
    float var = stats[64 + n] * (1.f / 8192.f) - mu * mu;
    float sc = rsqrtf(var + 128.f) * g[n];
    float x = (v[(r0 + rr) * 128 + c] - mu) * sc + bt[n];
    rows[rr][c] = x;
    v[(r0 + rr) * 128 + c] = x;  // normalized v for residual/concat
  }
  __syncthreads();
  float acc[8];
  const float bv = bias[c];
#pragma unroll
  for (int r = 0; r < 8; ++r) acc[r] = bv;
  for (int k4 = 0; k4 < 128; k4 += 4) {
    float w0 = W[(k4 + 0) * 128 + c], w1 = W[(k4 + 1) * 128 + c];
    float w2 = W[(k4 + 2) * 128 + c], w3 = W[(k4 + 3) * 128 + c];
#pragma unroll
    for (int r = 0; r < 8; ++r) {
      float4 x = *(const float4*)&rows[r][k4];
      acc[r] += x.x * w0 + x.y * w1 + x.z * w2 + x.w * w3;
    }
  }
#pragma unroll
  for (int r = 0; r < 8; ++r) out[(r0 + r) * 128 + c] = acc[r];
}

// ------------- g1 edge pass (MFMA, K 16->32 zero-pad, 2 j/block) -------------
__global__ __launch_bounds__(256) void k_edge_g1(const float* __restrict__ e0,
    const float* __restrict__ eW, const float* __restrict__ eb,
    const float* __restrict__ ev, bf16_t* __restrict__ e_ws,
    float* __restrict__ pve) {
  __shared__ bf16_t A0s[2][64][40];
  __shared__ bf16_t Os[2][64][136];
  const int b = blockIdx.x >> 5, j0 = (blockIdx.x & 31) * 2;
  const int tid = threadIdx.x;
  const int lane = tid & 63, w = tid >> 6;
  const int quad = lane >> 4, l16 = lane & 15;
#pragma unroll
  for (int t = 0; t < 2; ++t) {
    int idx = tid + t * 256;
    int row = idx >> 3, off = (idx & 7) * 4;
    int jc = off >> 4, k = off & 15;
    f32x4 x = *(const f32x4*)&e0[((b * 64 + row) * 64 + j0) * 16 + off];
    bf16x4 y;
#pragma unroll
    for (int r = 0; r < 4; ++r) y[r] = (bf16_t)x[r];
    *(bf16x4*)&A0s[jc][row][k] = y;
    bf16x4 z = {(bf16_t)0.f, (bf16_t)0.f, (bf16_t)0.f, (bf16_t)0.f};
    *(bf16x4*)&A0s[jc][row][16 + k] = z;
  }
  const int c0[2] = {w * 32 + quad * 4, w * 32 + 16 + quad * 4};
  bf16x8 wf[2];
#pragma unroll
  for (int nt = 0; nt < 2; ++nt) {
    const int c = w * 32 + nt * 16 + l16;
#pragma unroll
    for (int jj = 0; jj < 8; ++jj)
      wf[nt][jj] = (quad < 2) ? (bf16_t)eW[(quad * 8 + jj) * 128 + c] : (bf16_t)0.f;
  }
  f32x4 acc[2][4][2];
  {
    f32x4 ebv[2], evj[2][2], evi[4][2];
#pragma unroll
    for (int nt = 0; nt < 2; ++nt) {
      ebv[nt] = *(const f32x4*)&eb[c0[nt]];
#pragma unroll
      for (int jc = 0; jc < 2; ++jc)
        evj[jc][nt] = *(const f32x4*)&ev[(b * 64 + j0 + jc) * 128 + c0[nt]];
#pragma unroll
      for (int mt = 0; mt < 4; ++mt)
        evi[mt][nt] = *(const f32x4*)&ev[(b * 64 + mt * 16 + l16) * 128 + c0[nt]];
    }
#pragma unroll
    for (int jc = 0; jc < 2; ++jc)
#pragma unroll
      for (int mt = 0; mt < 4; ++mt)
#pragma unroll
        for (int nt = 0; nt < 2; ++nt)
          acc[jc][mt][nt] = ebv[nt] + evj[jc][nt] + evi[mt][nt];
  }
  __syncthreads();
#pragma unroll
  for (int jc = 0; jc < 2; ++jc) {
#pragma unroll
    for (int mt = 0; mt < 4; ++mt) {
      bf16x8 ef = *(const bf16x8*)&A0s[jc][mt * 16 + l16][quad * 8];
#pragma unroll
      for (int nt = 0; nt < 2; ++nt)
        acc[jc][mt][nt] = __builtin_amdgcn_mfma_f32_16x16x32_bf16(wf[nt], ef, acc[jc][mt][nt], 0, 0, 0);
    }
  }
#pragma unroll
  for (int jc = 0; jc < 2; ++jc) {
#pragma unroll
    for (int nt = 0; nt < 2; ++nt) {
      f32x4 ps = {0.f, 0.f, 0.f, 0.f};
#pragma unroll
      for (int mt = 0; mt < 4; ++mt) {
        const int i = mt * 16 + l16;
        bf16x4 outv;
#pragma unroll
        for (int r = 0; r < 4; ++r) {
          float vv = fmaxf(acc[jc][mt][nt][r], 0.f);
          ps[r] += vv;
          outv[r] = (bf16_t)vv;
        }
        *(bf16x4*)&Os[jc][i][c0[nt]] = outv;
      }
#pragma unroll
      for (int m = 1; m <= 8; m <<= 1) {
#pragma unroll
        for (int r = 0; r < 4; ++r) ps[r] += __shfl_xor(ps[r], m);
      }
      if (l16 == 0) *(f32x4*)&pve[(b * 64 + j0 + jc) * 128 + c0[nt]] = ps;
    }
  }
  __syncthreads();
#pragma unroll
  for (int t = 0; t < 8; ++t) {
    int idx = tid + t * 256;
    int row = idx >> 5, off = (idx & 31) * 8;
    int jc = off >> 7, c = off & 127;
    *(int4*)&e_ws[((b * 64 + row) * 64 + j0) * 128 + off] = *(const int4*)&Os[jc][row][c];
  }
}

// ------------- g1 v pass: relu(concat(pve[128], v0[32]) @ [160,128]) -------------
__global__ __launch_bounds__(128) void k_v_g1(const float* __restrict__ pve,
    const float* __restrict__ v0, const float* __restrict__ vW,
    const float* __restrict__ vb, float* __restrict__ v) {
  __shared__ float in[8][160];
  const int r0 = blockIdx.x * 8;
  const int c = threadIdx.x;
#pragma unroll
  for (int t = 0; t < 8; ++t) {
    int idx = c + t * 128;
    int rr = idx >> 7, k = idx & 127;
    in[rr][k] = pve[(r0 + rr) * 128 + k];
  }
#pragma unroll
  for (int t = 0; t < 2; ++t) {
    int idx = c + t * 128;
    int rr = idx >> 5, k = idx & 31;
    in[rr][128 + k] = v0[(r0 + rr) * 32 + k];
  }
  __syncthreads();
  float acc[8];
  const float bv = vb[c];
#pragma unroll
  for (int r = 0; r < 8; ++r) acc[r] = bv;
  for (int k4 = 0; k4 < 160; k4 += 4) {
    float w0 = vW[(k4 + 0) * 128 + c], w1 = vW[(k4 + 1) * 128 + c];
    float w2 = vW[(k4 + 2) * 128 + c], w3 = vW[(k4 + 3) * 128 + c];
#pragma unroll
    for (int r = 0; r < 8; ++r) {
      float4 x = *(const float4*)&in[r][k4];
      acc[r] += x.x * w0 + x.y * w1 + x.z * w2 + x.w * w3;
    }
  }
#pragma unroll
  for (int r = 0; r < 8; ++r) v[(r0 + r) * 128 + c] = fmaxf(acc[r], 0.f);
}

// ------------- inner edge pass: persistent, dbuf LDS, non-draining barriers -------------
// 1024 blocks; block handles (b = blk>>4, j = (blk&15)*4 + t, t=0..3).
// e += relu(e@W + eb + ev_i + ev_j); pve[b,j,:] = per-column sum (pre-residual).
__global__ __launch_bounds__(256) void k_edge_inner(bf16_t* __restrict__ e_ws,
    const bf16_t* __restrict__ Wt, const float* __restrict__ eb,
    const float* __restrict__ ev, float* __restrict__ pve) {
  __shared__ bf16_t As[2][64][136];  // double buffer, +8 pad
  const int tid = threadIdx.x;
  const int lane = tid & 63, w = tid >> 6;
  const int quad = lane >> 4, l16 = lane & 15;
  const int b = blockIdx.x >> 4;
  const int jb = (blockIdx.x & 15) * 4;
  const int c0[2] = {w * 32 + quad * 4, w * 32 + 16 + quad * 4};
  // persistent per-block loads: W frags, eb, ev_i (b-constant)
  bf16x8 wf[2][4];
#pragma unroll
  for (int nt = 0; nt < 2; ++nt)
#pragma unroll
    for (int ks = 0; ks < 4; ++ks)
      wf[nt][ks] = *(const bf16x8*)&Wt[(w * 32 + nt * 16 + l16) * 128 + ks * 32 + quad * 8];
  f32x4 ebv[2], evi[4][2];
#pragma unroll
  for (int nt = 0; nt < 2; ++nt) {
    ebv[nt] = *(const f32x4*)&eb[c0[nt]];
#pragma unroll
    for (int mt = 0; mt < 4; ++mt)
      evi[mt][nt] = *(const f32x4*)&ev[(b * 64 + mt * 16 + l16) * 128 + c0[nt]];
  }
  // preload tile 0 (j = jb): 16KB column, 4 int4/thread
  int4 stg[4];
  f32x4 evj[2];
#pragma unroll
  for (int u = 0; u < 4; ++u) {
    int idx = tid + u * 256;
    stg[u] = *(const int4*)&e_ws[((b * 64 + (idx >> 4)) * 64 + jb) * 128 + (idx & 15) * 8];
  }
#pragma unroll
  for (int nt = 0; nt < 2; ++nt)
    evj[nt] = *(const f32x4*)&ev[(b * 64 + jb) * 128 + c0[nt]];
#pragma unroll
  for (int u = 0; u < 4; ++u) {
    int idx = tid + u * 256;
    *(int4*)&As[0][idx >> 4][(idx & 15) * 8] = stg[u];
  }
  bar_lgkm();
#pragma unroll
  for (int t = 0; t < 4; ++t) {
    const int X = t & 1, j = jb + t;
    // prefetch next tile (stays in flight across all barriers below)
    int4 stg2[4];
    f32x4 evj2[2];
    if (t < 3) {
#pragma unroll
      for (int u = 0; u < 4; ++u) {
        int idx = tid + u * 256;
        stg2[u] = *(const int4*)&e_ws[((b * 64 + (idx >> 4)) * 64 + (j + 1)) * 128 + (idx & 15) * 8];
      }
#pragma unroll
      for (int nt = 0; nt < 2; ++nt)
        evj2[nt] = *(const f32x4*)&ev[(b * 64 + j + 1) * 128 + c0[nt]];
    }
    // acc init = eb + ev_j + ev_i; MFMA: D[c][i] = sum_k Wt[c][k] * e[i][k]
    f32x4 acc[4][2];
#pragma unroll
    for (int mt = 0; mt < 4; ++mt)
#pragma unroll
      for (int nt = 0; nt < 2; ++nt)
        acc[mt][nt] = ebv[nt] + evj[nt] + evi[mt][nt];
#pragma unroll
    for (int ks = 0; ks < 4; ++ks) {
      bf16x8 ef[4];
#pragma unroll
      for (int mt = 0; mt < 4; ++mt)
        ef[mt] = *(const bf16x8*)&As[X][mt * 16 + l16][ks * 32 + quad * 8];
#pragma unroll
      for (int mt = 0; mt < 4; ++mt)
#pragma unroll
        for (int nt = 0; nt < 2; ++nt)
          acc[mt][nt] = __builtin_amdgcn_mfma_f32_16x16x32_bf16(wf[nt][ks], ef[mt], acc[mt][nt], 0, 0, 0);
    }
    bar_lgkm();  // all MFMA frag reads of As[X] done (LDS-only dep)
    // epilogue: relu, pve, residual from LDS, packed b64 writes (own cells)
#pragma unroll
    for (int nt = 0; nt < 2; ++nt) {
      f32x4 ps = {0.f, 0.f, 0.f, 0.f};
#pragma unroll
      for (int mt = 0; mt < 4; ++mt) {
        const int i = mt * 16 + l16;
        bf16x4 eo = *(const bf16x4*)&As[X][i][c0[nt]];
        bf16x4 outv;
#pragma unroll
        for (int r = 0; r < 4; ++r) {
          float vv = fmaxf(acc[mt][nt][r], 0.f);
          ps[r] += vv;                            // pve is pre-residual
          outv[r] = (bf16_t)(vv + (float)eo[r]);  // residual
        }
        *(bf16x4*)&As[X][i][c0[nt]] = outv;
      }
#pragma unroll
      for (int m = 1; m <= 8; m <<= 1) {
#pragma unroll
        for (int r = 0; r < 4; ++r) ps[r] += __shfl_xor(ps[r], m);
      }
      if (l16 == 0) *(f32x4*)&pve[(b * 64 + j) * 128 + c0[nt]] = ps;
    }
    bar_lgkm();  // As[X] fully updated (LDS-only dep)
    // coalesced write-back of As[X], then stage prefetched tile into As[1-X]
#pragma unroll
    for (int u = 0; u < 4; ++u) {
      int idx = tid + u * 256;
      *(int4*)&e_ws[((b * 64 + (idx >> 4)) * 64 + j) * 128 + (idx & 15) * 8] =
          *(const int4*)&As[X][idx >> 4][(idx & 15) * 8];
    }
    if (t < 3) {
#pragma unroll
      for (int u = 0; u < 4; ++u) {
        int idx = tid + u * 256;
        *(int4*)&As[1 - X][idx >> 4][(idx & 15) * 8] = stg2[u];
      }
      evj[0] = evj2[0];
      evj[1] = evj2[1];
    }
    bar_lgkm();  // As[1-X] staged for next iter; all As[X] reads done
  }
}

// ------------- inner v pass: v = relu(concat(pve,v)@[256,128]+vb) + v; BN stats -------------
__global__ __launch_bounds__(128) void k_v_inner(const float* __restrict__ pve,
    float* __restrict__ v, const float* __restrict__ vW,
    const float* __restrict__ vb, float* __restrict__ stats) {
  __shared__ float in[8][256];
  __shared__ float outs[8][132];  // +4 pad
  const int r0 = blockIdx.x * 8;
  const int c = threadIdx.x;
#pragma unroll
  for (int t = 0; t < 8; ++t) {
    int idx = c + t * 128;
    int rr = idx >> 7, k = idx & 127;
    in[rr][k] = pve[(r0 + rr) * 128 + k];
    in[rr][128 + k] = v[(r0 + rr) * 128 + k];
  }
  __syncthreads();
  float acc[8];
  const float bv = vb[c];
#pragma unroll
  for (int r = 0; r < 8; ++r) acc[r] = bv;
  for (int k4 = 0; k4 < 256; k4 += 4) {
    float w0 = vW[(k4 + 0) * 128 + c], w1 = vW[(k4 + 1) * 128 + c];
    float w2 = vW[(k4 + 2) * 128 + c], w3 = vW[(k4 + 3) * 128 + c];
#pragma unroll
    for (int r = 0; r < 8; ++r) {
      float4 x = *(const float4*)&in[r][k4];
      acc[r] += x.x * w0 + x.y * w1 + x.z * w2 + x.w * w3;
    }
  }
#pragma unroll
  for (int r = 0; r < 8; ++r) {
    float val = fmaxf(acc[r], 0.f) + in[r][128 + c];  // relu + residual
    outs[r][c] = val;
    v[(r0 + r) * 128 + c] = val;
  }
  __syncthreads();
  if (c < 8) {  // per-(b,n) partial sums for BN stats over (B,D)
    float s = 0.f, s2 = 0.f;
    for (int k = 0; k < 128; ++k) { float x = outs[c][k]; s += x; s2 += x * x; }
    int n = (r0 + c) & 63;
    atomicAdd(&stats[n], s);
    atomicAdd(&stats[64 + n], s2);
  }
}

// ------------- g3 edge (fused BN + ev3): e3 = e.W3 + eb + ev3_i + ev3_j -------------
__global__ __launch_bounds__(256) void k_edge_g3(const bf16_t* __restrict__ e_ws,
    const float* __restrict__ vv, const float* __restrict__ stats3,
    const float* __restrict__ g, const float* __restrict__ bt,
    const float* __restrict__ evW3, const float* __restrict__ evb3,
    const float* __restrict__ eW3, const float* __restrict__ eb3,
    float* __restrict__ out_e, float* __restrict__ pve3) {
  __shared__ float vbn[64][132];  // +4 pad
  __shared__ float scs[64], shs[64];
  __shared__ float W3e[128], W3ee[128];
  __shared__ float ev3s[64];
  const int b = blockIdx.x >> 6, i = blockIdx.x & 63;
  const int tid = threadIdx.x;
  if (tid < 64) {
    float mu = stats3[tid] * (1.f / 8192.f);
    float var = stats3[64 + tid] * (1.f / 8192.f) - mu * mu;
    float sc = rsqrtf(var + 128.f) * g[tid];
    scs[tid] = sc;
    shs[tid] = bt[tid] - mu * sc;
  }
  if (tid < 128) W3ee[tid] = eW3[tid];
  else W3e[tid - 128] = evW3[tid - 128];
  __syncthreads();
#pragma unroll
  for (int t = 0; t < 8; ++t) {
    int idx = t * 1024 + tid * 4;
    int row = idx >> 7, c = idx & 127;
    f32x4 x = *(const f32x4*)&vv[(b * 64 + row) * 128 + c];
    f32x4 y = x * scs[row] + shs[row];
    *(f32x4*)&vbn[row][c] = y;
  }
  __syncthreads();
  {
    int r = tid >> 2, q = tid & 3;
    float a = 0.f;
#pragma unroll
    for (int u = 0; u < 32; ++u) a += vbn[r][q * 32 + u] * W3e[q * 32 + u];
    a += __shfl_xor(a, 1);
    a += __shfl_xor(a, 2);
    if (q == 0) ev3s[r] = a + evb3[0];
  }
  __syncthreads();
  {
    const int j = tid >> 2, cs = (tid & 3) * 32;
    const bf16_t* ep = &e_ws[(size_t)((b * 64 + i) * 64 + j) * 128 + cs];
    float acc = 0.f;
#pragma unroll
    for (int t = 0; t < 4; ++t) {
      bf16x8 x = *(const bf16x8*)&ep[t * 8];
#pragma unroll
      for (int u = 0; u < 8; ++u) acc += (float)x[u] * W3ee[cs + t * 8 + u];
    }
    acc += __shfl_xor(acc, 1);
    acc += __shfl_xor(acc, 2);
    if ((tid & 3) == 0) {
      float s = acc + eb3[0] + ev3s[i] + ev3s[j];
      out_e[(b * 64 + i) * 64 + j] = s;
      atomicAdd(&pve3[b * 64 + j], s);
    }
  }
}

// ------------- g3 v (fused BN): v3 = pve3*W[0] + vbn.W[1:] + b -------------
__global__ __launch_bounds__(256) void k_v_g3(const float* __restrict__ vv,
    const float* __restrict__ stats3, const float* __restrict__ g,
    const float* __restrict__ bt, const float* __restrict__ pve3,
    const float* __restrict__ vW, const float* __restrict__ vb,
    float* __restrict__ out_v) {
  int r = blockIdx.x * 4 + (threadIdx.x >> 6);
  int lane = threadIdx.x & 63;
  int n = r & 63;
  float mu = stats3[n] * (1.f / 8192.f);
  float var = stats3[64 + n] * (1.f / 8192.f) - mu * mu;
  float sc = rsqrtf(var + 128.f) * g[n];
  float sh = bt[n] - mu * sc;
  float x1 = vv[r * 128 + lane] * sc + sh;
  float x2 = vv[r * 128 + 64 + lane] * sc + sh;
  float acc = x1 * vW[1 + lane] + x2 * vW[65 + lane];
#pragma unroll
  for (int m = 1; m < 64; m <<= 1) acc += __shfl_xor(acc, m);
  if (lane == 0) out_v[r] = acc + pve3[r] * vW[0] + vb[0];
}

extern "C" void kernel_launch(void* const* d_in, const int* in_sizes, int n_in,
                              void* d_out, int out_size, void* d_ws, size_t ws_size,
                              hipStream_t stream) {
  const float* in_v    = (const float*)d_in[0];
  const float* in_e    = (const float*)d_in[1];
  const float* bn_in_g = (const float*)d_in[2];
  const float* bn_in_b = (const float*)d_in[3];
  const float* g1_evW  = (const float*)d_in[4];
  const float* g1_evb  = (const float*)d_in[5];
  const float* g1_eW   = (const float*)d_in[6];
  const float* g1_eb   = (const float*)d_in[7];
  const float* g1_vW   = (const float*)d_in[8];
  const float* g1_vb   = (const float*)d_in[9];
  const float* inn_evW = (const float*)d_in[10];
  const float* inn_evb = (const float*)d_in[11];
  const float* inn_eW  = (const float*)d_in[12];
  const float* inn_eb  = (const float*)d_in[13];
  const float* inn_vW  = (const float*)d_in[14];
  const float* inn_vb  = (const float*)d_in[15];
  const float* bn_g    = (const float*)d_in[16];
  const float* bn_b    = (const float*)d_in[17];
  const float* g3_evW  = (const float*)d_in[18];
  const float* g3_evb  = (const float*)d_in[19];
  const float* g3_eW   = (const float*)d_in[20];
  const float* g3_eb   = (const float*)d_in[21];
  const float* g3_vW   = (const float*)d_in[22];
  const float* g3_vb   = (const float*)d_in[23];

  char* ws = (char*)d_ws;
  bf16_t* e_ws = (bf16_t*)(ws);                       // 64MB : e as bf16
  float* v     = (float*)(ws + 67108864);             // 2MB
  float* ev    = (float*)(ws + 69206016);             // 2MB
  float* pve   = (float*)(ws + 71303168);             // 2MB
  float* v0    = (float*)(ws + 73400320);             // 512KB
  bf16_t* Wt   = (bf16_t*)(ws + 73924608);            // 128KB
  float* pve3  = (float*)(ws + 74072064);             // 16KB
  float* stats = (float*)(ws + 74088448);             // 2KB (4 layers x 128 f32)

  float* out_v = (float*)d_out;          // [B,N,1] = 4096
  float* out_e = (float*)d_out + 4096;   // [B,N,N,1] = 262144

  k_prep<<<265, 256, 0, stream>>>(in_v, bn_in_g, bn_in_b, inn_eW, v0, Wt, pve3, stats);

  // ---- g1 ----
  k_ev<32><<<512, 128, 0, stream>>>(v0, g1_evW, g1_evb, ev);
  k_edge_g1<<<2048, 256, 0, stream>>>(in_e, g1_eW, g1_eb, ev, e_ws, pve);
  k_v_g1<<<512, 128, 0, stream>>>(pve, v0, g1_vW, g1_vb, v);

  // ---- inner layers (BN of layer l-1 fused into layer l's ev kernel) ----
  for (int l = 0; l < 4; ++l) {
    if (l == 0)
      k_ev<128><<<512, 128, 0, stream>>>(v, inn_evW, inn_evb, ev);
    else
      k_evbn<<<512, 128, 0, stream>>>(v, stats + (l - 1) * 128, bn_g + (l - 1) * 64,
                                      bn_b + (l - 1) * 64, inn_evW + l * 16384,
                                      inn_evb + l * 128, ev);
    k_edge_inner<<<1024, 256, 0, stream>>>(e_ws, Wt + l * 16384, inn_eb + l * 128, ev, pve);
    k_v_inner<<<512, 128, 0, stream>>>(pve, v, inn_vW + l * 32768, inn_vb + l * 128,
                                       stats + l * 128);
  }

  // ---- g3 (BN of layer 3 applied on the fly) ----
  k_edge_g3<<<4096, 256, 0, stream>>>(e_ws, v, stats + 384, bn_g + 192, bn_b + 192,
                                      g3_evW, g3_evb, g3_eW, g3_eb, out_e, pve3);
  k_v_g3<<<1024, 256, 0, stream>>>(v, stats + 384, bn_g + 192, bn_b + 192, pve3,
                                   g3_vW, g3_vb, out_v);
}

// Round 6
// 455.133 us; speedup vs baseline: 1.1688x; 1.0043x over previous
//
#include <hip/hip_runtime.h>
#include <hip/hip_bf16.h>

// GraphVertEdgeNet on MI355X. B=64, N=64, VF=32, EF=16, DV=DE=128, LN=4.
// e stored bf16 in ws (64MB). Inner edge kernel: persistent blocks (2 pairs of
// 2 j-columns), dbuf LDS, lgkmcnt-only barriers. Layer 3 fuses the g3 edge dot
// (edot = e_new . eW3) into the epilogue and skips the 64MB e write-back.
// g3 finishes in one 64-block kernel (BN + ev3 + out_e + pve3 + out_v).

typedef __bf16 bf16_t;
typedef __bf16 bf16x8 __attribute__((ext_vector_type(8)));
typedef __bf16 bf16x4 __attribute__((ext_vector_type(4)));
typedef float f32x4 __attribute__((ext_vector_type(4)));

// Barrier that does NOT drain vmcnt: safe when cross-thread deps are LDS-only.
__device__ __forceinline__ void bar_lgkm() {
  asm volatile("s_waitcnt lgkmcnt(0)\n\ts_barrier" ::: "memory");
}

// ---------------- prep: input BN (v0), Wt transpose, zero stats ----------------
__global__ __launch_bounds__(256) void k_prep(const float* __restrict__ vin,
    const float* __restrict__ g, const float* __restrict__ bt,
    const float* __restrict__ eW, float* __restrict__ v0,
    bf16_t* __restrict__ Wt, float* __restrict__ stats) {
  const int blk = blockIdx.x, tid = threadIdx.x;
  if (blk < 8) {  // BatchNorm1d(N*VF) over batch, ch = 0..2047
    int ch = blk * 256 + tid;
    float s = 0.f, s2 = 0.f;
    for (int b = 0; b < 64; ++b) { float x = vin[b * 2048 + ch]; s += x; s2 += x * x; }
    float mu = s * (1.f / 64.f);
    float var = s2 * (1.f / 64.f) - mu * mu;  // biased var
    float sc = rsqrtf(var + 1e-5f) * g[ch];
    float bb = bt[ch];
    for (int b = 0; b < 64; ++b) {
      float x = vin[b * 2048 + ch];
      v0[b * 2048 + ch] = (x - mu) * sc + bb;
    }
  } else if (blk < 264) {  // Wt[l][n][k] = eW[l][k][n] as bf16
    int idx = (blk - 8) * 256 + tid;  // 4*128*128 = 65536
    int l = idx >> 14, r = idx & 16383, n = r >> 7, k = r & 127;
    Wt[idx] = (bf16_t)eW[(l << 14) + (k << 7) + n];
  } else {  // zero stats (512 f32)
    for (int i = tid; i < 512; i += 256) stats[i] = 0.f;
  }
}

// ------------- ev = v_in @ W + bias : [4096,K] @ [K,128] -> [4096,128] -------------
template <int K>
__global__ __launch_bounds__(128) void k_ev(const float* __restrict__ v_in,
    const float* __restrict__ W, const float* __restrict__ bias,
    float* __restrict__ out) {
  __shared__ float rows[8][K];
  const int r0 = blockIdx.x * 8;
  const int c = threadIdx.x;
  for (int idx = c; idx < 8 * K; idx += 128) {
    int rr = idx / K, kk = idx % K;
    rows[rr][kk] = v_in[(r0 + rr) * K + kk];
  }
  __syncthreads();
  float acc[8];
  const float bv = bias[c];
#pragma unroll
  for (int r = 0; r < 8; ++r) acc[r] = bv;
  for (int k4 = 0; k4 < K; k4 += 4) {
    float w0 = W[(k4 + 0) * 128 + c], w1 = W[(k4 + 1) * 128 + c];
    float w2 = W[(k4 + 2) * 128 + c], w3 = W[(k4 + 3) * 128 + c];
#pragma unroll
    for (int r = 0; r < 8; ++r) {
      float4 x = *(const float4*)&rows[r][k4];
      acc[r] += x.x * w0 + x.y * w1 + x.z * w2 + x.w * w3;
    }
  }
#pragma unroll
  for (int r = 0; r < 8; ++r) out[(r0 + r) * 128 + c] = acc[r];
}

// ------------- fused BN(prev layer) + ev matmul: normalizes v in place -------------
__global__ __launch_bounds__(128) void k_evbn(float* __restrict__ v,
    const float* __restrict__ stats, const float* __restrict__ g,
    const float* __restrict__ bt, const float* __restrict__ W,
    const float* __restrict__ bias, float* __restrict__ out) {
  __shared__ float rows[8][128];
  const int r0 = blockIdx.x * 8;
  const int c = threadIdx.x;
#pragma unroll
  for (int rr = 0; rr < 8; ++rr) {
    int n = (r0 + rr) & 63;
    float mu = stats[n] * (1.f / 8192.f);
    float var = stats[64 + n] * (1.f / 8192.f) - mu * mu;
    float sc = rsqrtf(var + 128.f) * g[n];
    float x = (v[(r0 + rr) * 128 + c] - mu) * sc + bt[n];
    rows[rr][c] = x;
    v[(r0 + rr) * 128 + c] = x;  // normalized v for residual/concat
  }
  __syncthreads();
  float acc[8];
  const float bv = bias[c];
#pragma unroll
  for (int r = 0; r < 8; ++r) acc[r] = bv;
  for (int k4 = 0; k4 < 128; k4 += 4) {
    float w0 = W[(k4 + 0) * 128 + c], w1 = W[(k4 + 1) * 128 + c];
    float w2 = W[(k4 + 2) * 128 + c], w3 = W[(k4 + 3) * 128 + c];
#pragma unroll
    for (int r = 0; r < 8; ++r) {
      float4 x = *(const float4*)&rows[r][k4];
      acc[r] += x.x * w0 + x.y * w1 + x.z * w2 + x.w * w3;
    }
  }
#pragma unroll
  for (int r = 0; r < 8; ++r) out[(r0 + r) * 128 + c] = acc[r];
}

// ------------- g1 edge pass (MFMA, K 16->32 zero-pad, 2 j/block) -------------
__global__ __launch_bounds__(256) void k_edge_g1(const float* __restrict__ e0,
    const float* __restrict__ eW, const float* __restrict__ eb,
    const float* __restrict__ ev, bf16_t* __restrict__ e_ws,
    float* __restrict__ pve) {
  __shared__ bf16_t A0s[2][64][40];
  __shared__ bf16_t Os[2][64][136];
  const int b = blockIdx.x >> 5, j0 = (blockIdx.x & 31) * 2;
  const int tid = threadIdx.x;
  const int lane = tid & 63, w = tid >> 6;
  const int quad = lane >> 4, l16 = lane & 15;
#pragma unroll
  for (int t = 0; t < 2; ++t) {
    int idx = tid + t * 256;
    int row = idx >> 3, off = (idx & 7) * 4;
    int jc = off >> 4, k = off & 15;
    f32x4 x = *(const f32x4*)&e0[((b * 64 + row) * 64 + j0) * 16 + off];
    bf16x4 y;
#pragma unroll
    for (int r = 0; r < 4; ++r) y[r] = (bf16_t)x[r];
    *(bf16x4*)&A0s[jc][row][k] = y;
    bf16x4 z = {(bf16_t)0.f, (bf16_t)0.f, (bf16_t)0.f, (bf16_t)0.f};
    *(bf16x4*)&A0s[jc][row][16 + k] = z;
  }
  const int c0[2] = {w * 32 + quad * 4, w * 32 + 16 + quad * 4};
  bf16x8 wf[2];
#pragma unroll
  for (int nt = 0; nt < 2; ++nt) {
    const int c = w * 32 + nt * 16 + l16;
#pragma unroll
    for (int jj = 0; jj < 8; ++jj)
      wf[nt][jj] = (quad < 2) ? (bf16_t)eW[(quad * 8 + jj) * 128 + c] : (bf16_t)0.f;
  }
  f32x4 acc[2][4][2];
  {
    f32x4 ebv[2], evj[2][2], evi[4][2];
#pragma unroll
    for (int nt = 0; nt < 2; ++nt) {
      ebv[nt] = *(const f32x4*)&eb[c0[nt]];
#pragma unroll
      for (int jc = 0; jc < 2; ++jc)
        evj[jc][nt] = *(const f32x4*)&ev[(b * 64 + j0 + jc) * 128 + c0[nt]];
#pragma unroll
      for (int mt = 0; mt < 4; ++mt)
        evi[mt][nt] = *(const f32x4*)&ev[(b * 64 + mt * 16 + l16) * 128 + c0[nt]];
    }
#pragma unroll
    for (int jc = 0; jc < 2; ++jc)
#pragma unroll
      for (int mt = 0; mt < 4; ++mt)
#pragma unroll
        for (int nt = 0; nt < 2; ++nt)
          acc[jc][mt][nt] = ebv[nt] + evj[jc][nt] + evi[mt][nt];
  }
  __syncthreads();
#pragma unroll
  for (int jc = 0; jc < 2; ++jc) {
#pragma unroll
    for (int mt = 0; mt < 4; ++mt) {
      bf16x8 ef = *(const bf16x8*)&A0s[jc][mt * 16 + l16][quad * 8];
#pragma unroll
      for (int nt = 0; nt < 2; ++nt)
        acc[jc][mt][nt] = __builtin_amdgcn_mfma_f32_16x16x32_bf16(wf[nt], ef, acc[jc][mt][nt], 0, 0, 0);
    }
  }
#pragma unroll
  for (int jc = 0; jc < 2; ++jc) {
#pragma unroll
    for (int nt = 0; nt < 2; ++nt) {
      f32x4 ps = {0.f, 0.f, 0.f, 0.f};
#pragma unroll
      for (int mt = 0; mt < 4; ++mt) {
        const int i = mt * 16 + l16;
        bf16x4 outv;
#pragma unroll
        for (int r = 0; r < 4; ++r) {
          float vv = fmaxf(acc[jc][mt][nt][r], 0.f);
          ps[r] += vv;
          outv[r] = (bf16_t)vv;
        }
        *(bf16x4*)&Os[jc][i][c0[nt]] = outv;
      }
#pragma unroll
      for (int m = 1; m <= 8; m <<= 1) {
#pragma unroll
        for (int r = 0; r < 4; ++r) ps[r] += __shfl_xor(ps[r], m);
      }
      if (l16 == 0) *(f32x4*)&pve[(b * 64 + j0 + jc) * 128 + c0[nt]] = ps;
    }
  }
  __syncthreads();
#pragma unroll
  for (int t = 0; t < 8; ++t) {
    int idx = tid + t * 256;
    int row = idx >> 5, off = (idx & 31) * 8;
    int jc = off >> 7, c = off & 127;
    *(int4*)&e_ws[((b * 64 + row) * 64 + j0) * 128 + off] = *(const int4*)&Os[jc][row][c];
  }
}

// ------------- fused g1-v + layer0-ev: v = relu(concat(pve,v0)@vW+vb); ev = v@evW+evb -------------
__global__ __launch_bounds__(128) void k_vg1_ev(const float* __restrict__ pve,
    const float* __restrict__ v0, const float* __restrict__ vW,
    const float* __restrict__ vb, const float* __restrict__ evW,
    const float* __restrict__ evb, float* __restrict__ v, float* __restrict__ ev) {
  __shared__ float in[8][160];
  __shared__ float vr[8][128];
  const int r0 = blockIdx.x * 8;
  const int c = threadIdx.x;
#pragma unroll
  for (int t = 0; t < 8; ++t) {
    int idx = c + t * 128;
    int rr = idx >> 7, k = idx & 127;
    in[rr][k] = pve[(r0 + rr) * 128 + k];
  }
#pragma unroll
  for (int t = 0; t < 2; ++t) {
    int idx = c + t * 128;
    int rr = idx >> 5, k = idx & 31;
    in[rr][128 + k] = v0[(r0 + rr) * 32 + k];
  }
  __syncthreads();
  float acc[8];
  const float bv = vb[c];
#pragma unroll
  for (int r = 0; r < 8; ++r) acc[r] = bv;
  for (int k4 = 0; k4 < 160; k4 += 4) {
    float w0 = vW[(k4 + 0) * 128 + c], w1 = vW[(k4 + 1) * 128 + c];
    float w2 = vW[(k4 + 2) * 128 + c], w3 = vW[(k4 + 3) * 128 + c];
#pragma unroll
    for (int r = 0; r < 8; ++r) {
      float4 x = *(const float4*)&in[r][k4];
      acc[r] += x.x * w0 + x.y * w1 + x.z * w2 + x.w * w3;
    }
  }
#pragma unroll
  for (int r = 0; r < 8; ++r) {
    float val = fmaxf(acc[r], 0.f);
    vr[r][c] = val;
    v[(r0 + r) * 128 + c] = val;
  }
  __syncthreads();
  float acc2[8];
  const float bv2 = evb[c];
#pragma unroll
  for (int r = 0; r < 8; ++r) acc2[r] = bv2;
  for (int k4 = 0; k4 < 128; k4 += 4) {
    float w0 = evW[(k4 + 0) * 128 + c], w1 = evW[(k4 + 1) * 128 + c];
    float w2 = evW[(k4 + 2) * 128 + c], w3 = evW[(k4 + 3) * 128 + c];
#pragma unroll
    for (int r = 0; r < 8; ++r) {
      float4 x = *(const float4*)&vr[r][k4];
      acc2[r] += x.x * w0 + x.y * w1 + x.z * w2 + x.w * w3;
    }
  }
#pragma unroll
  for (int r = 0; r < 8; ++r) ev[(r0 + r) * 128 + c] = acc2[r];
}

// ------------- inner edge pass: persistent (2 pairs of 2 cols), dbuf, lgkm barriers -------------
// 1024 blocks: b = blk>>4, jg = (blk&15)*4. e += relu(e@W + eb + ev_i + ev_j).
// LAST: instead of e write-back, computes edot[b][j][i] = dot(e_new[b,i,j,:], eW3).
template <bool LAST>
__global__ __launch_bounds__(256) void k_edge_inner(bf16_t* __restrict__ e_ws,
    const bf16_t* __restrict__ Wt, const float* __restrict__ eb,
    const float* __restrict__ ev, float* __restrict__ pve,
    const float* __restrict__ eW3, float* __restrict__ edt) {
  __shared__ bf16_t As[2][2][64][136];  // [buf][jc][row][col], +8 pad
  __shared__ float W3s[128];
  const int tid = threadIdx.x;
  const int lane = tid & 63, w = tid >> 6;
  const int quad = lane >> 4, l16 = lane & 15;
  const int b = blockIdx.x >> 4;
  const int jg = (blockIdx.x & 15) * 4;
  const int c0[2] = {w * 32 + quad * 4, w * 32 + 16 + quad * 4};
  // persistent per-block loads
  bf16x8 wf[2][4];
#pragma unroll
  for (int nt = 0; nt < 2; ++nt)
#pragma unroll
    for (int ks = 0; ks < 4; ++ks)
      wf[nt][ks] = *(const bf16x8*)&Wt[(w * 32 + nt * 16 + l16) * 128 + ks * 32 + quad * 8];
  f32x4 ebv[2], evi[4][2];
#pragma unroll
  for (int nt = 0; nt < 2; ++nt) {
    ebv[nt] = *(const f32x4*)&eb[c0[nt]];
#pragma unroll
    for (int mt = 0; mt < 4; ++mt)
      evi[mt][nt] = *(const f32x4*)&ev[(b * 64 + mt * 16 + l16) * 128 + c0[nt]];
  }
  if (LAST) {
    if (tid < 128) W3s[tid] = eW3[tid];
  }
  // preload pair 0 (cols jg, jg+1): 512B per row, 8 int4/thread
  int4 stg[8];
#pragma unroll
  for (int u = 0; u < 8; ++u) {
    int idx = tid + u * 256;
    stg[u] = *(const int4*)&e_ws[((b * 64 + (idx >> 5)) * 64 + jg) * 128 + (idx & 31) * 8];
  }
  f32x4 evj[2][2];
#pragma unroll
  for (int jc = 0; jc < 2; ++jc)
#pragma unroll
    for (int nt = 0; nt < 2; ++nt)
      evj[jc][nt] = *(const f32x4*)&ev[(b * 64 + jg + jc) * 128 + c0[nt]];
#pragma unroll
  for (int u = 0; u < 8; ++u) {
    int idx = tid + u * 256;
    int off = (idx & 31) * 8;
    *(int4*)&As[0][off >> 7][idx >> 5][off & 127] = stg[u];
  }
  bar_lgkm();
#pragma unroll
  for (int p = 0; p < 2; ++p) {
    const int j0 = jg + p * 2;
    // prefetch pair 1 while pair 0 computes (stays in flight across barriers)
    int4 stg2[8];
    f32x4 evj2[2][2];
    if (p == 0) {
#pragma unroll
      for (int u = 0; u < 8; ++u) {
        int idx = tid + u * 256;
        stg2[u] = *(const int4*)&e_ws[((b * 64 + (idx >> 5)) * 64 + jg + 2) * 128 + (idx & 31) * 8];
      }
#pragma unroll
      for (int jc = 0; jc < 2; ++jc)
#pragma unroll
        for (int nt = 0; nt < 2; ++nt)
          evj2[jc][nt] = *(const f32x4*)&ev[(b * 64 + jg + 2 + jc) * 128 + c0[nt]];
    }
    // acc init = eb + ev_j + ev_i; MFMA D[c][i]
    f32x4 acc[2][4][2];
#pragma unroll
    for (int jc = 0; jc < 2; ++jc)
#pragma unroll
      for (int mt = 0; mt < 4; ++mt)
#pragma unroll
        for (int nt = 0; nt < 2; ++nt)
          acc[jc][mt][nt] = ebv[nt] + evj[jc][nt] + evi[mt][nt];
#pragma unroll
    for (int ks = 0; ks < 4; ++ks) {
      bf16x8 ef[2][4];
#pragma unroll
      for (int jc = 0; jc < 2; ++jc)
#pragma unroll
        for (int mt = 0; mt < 4; ++mt)
          ef[jc][mt] = *(const bf16x8*)&As[p][jc][mt * 16 + l16][ks * 32 + quad * 8];
#pragma unroll
      for (int jc = 0; jc < 2; ++jc)
#pragma unroll
        for (int mt = 0; mt < 4; ++mt)
#pragma unroll
          for (int nt = 0; nt < 2; ++nt)
            acc[jc][mt][nt] = __builtin_amdgcn_mfma_f32_16x16x32_bf16(wf[nt][ks], ef[jc][mt], acc[jc][mt][nt], 0, 0, 0);
    }
    bar_lgkm();  // all MFMA reads of As[p] done (LDS-only dep)
    // epilogue: relu, pve, residual from LDS, packed b64 writes
#pragma unroll
    for (int jc = 0; jc < 2; ++jc) {
#pragma unroll
      for (int nt = 0; nt < 2; ++nt) {
        f32x4 ps = {0.f, 0.f, 0.f, 0.f};
#pragma unroll
        for (int mt = 0; mt < 4; ++mt) {
          const int i = mt * 16 + l16;
          bf16x4 eo = *(const bf16x4*)&As[p][jc][i][c0[nt]];
          bf16x4 outv;
#pragma unroll
          for (int r = 0; r < 4; ++r) {
            float vv = fmaxf(acc[jc][mt][nt][r], 0.f);
            ps[r] += vv;                            // pve is pre-residual
            outv[r] = (bf16_t)(vv + (float)eo[r]);  // residual
          }
          *(bf16x4*)&As[p][jc][i][c0[nt]] = outv;
        }
#pragma unroll
        for (int m = 1; m <= 8; m <<= 1) {
#pragma unroll
          for (int r = 0; r < 4; ++r) ps[r] += __shfl_xor(ps[r], m);
        }
        if (l16 == 0) *(f32x4*)&pve[(b * 64 + j0 + jc) * 128 + c0[nt]] = ps;
      }
    }
    bar_lgkm();  // As[p] fully updated
    if (!LAST) {
      // coalesced e write-back: 512B per row
#pragma unroll
      for (int u = 0; u < 8; ++u) {
        int idx = tid + u * 256;
        int off = (idx & 31) * 8;
        *(int4*)&e_ws[((b * 64 + (idx >> 5)) * 64 + j0) * 128 + off] =
            *(const int4*)&As[p][off >> 7][idx >> 5][off & 127];
      }
    } else {
      // edot[b][j][i] = dot(e_new[b,i,j,:], W3)
      const int i = tid >> 2, q = tid & 3;
#pragma unroll
      for (int jc = 0; jc < 2; ++jc) {
        float d = 0.f;
#pragma unroll
        for (int u = 0; u < 32; ++u) d += (float)As[p][jc][i][q * 32 + u] * W3s[q * 32 + u];
        d += __shfl_xor(d, 1);
        d += __shfl_xor(d, 2);
        if (q == 0) edt[(b * 64 + j0 + jc) * 64 + i] = d;
      }
    }
    if (p == 0) {  // stage prefetched pair into buffer 1
#pragma unroll
      for (int u = 0; u < 8; ++u) {
        int idx = tid + u * 256;
        int off = (idx & 31) * 8;
        *(int4*)&As[1][off >> 7][idx >> 5][off & 127] = stg2[u];
      }
#pragma unroll
      for (int jc = 0; jc < 2; ++jc) {
        evj[jc][0] = evj2[jc][0];
        evj[jc][1] = evj2[jc][1];
      }
      bar_lgkm();
    }
  }
}

// ------------- inner v pass: v = relu(concat(pve,v)@[256,128]+vb) + v; BN stats -------------
__global__ __launch_bounds__(128) void k_v_inner(const float* __restrict__ pve,
    float* __restrict__ v, const float* __restrict__ vW,
    const float* __restrict__ vb, float* __restrict__ stats) {
  __shared__ float in[8][256];
  __shared__ float outs[8][132];  // +4 pad
  const int r0 = blockIdx.x * 8;
  const int c = threadIdx.x;
#pragma unroll
  for (int t = 0; t < 8; ++t) {
    int idx = c + t * 128;
    int rr = idx >> 7, k = idx & 127;
    in[rr][k] = pve[(r0 + rr) * 128 + k];
    in[rr][128 + k] = v[(r0 + rr) * 128 + k];
  }
  __syncthreads();
  float acc[8];
  const float bv = vb[c];
#pragma unroll
  for (int r = 0; r < 8; ++r) acc[r] = bv;
  for (int k4 = 0; k4 < 256; k4 += 4) {
    float w0 = vW[(k4 + 0) * 128 + c], w1 = vW[(k4 + 1) * 128 + c];
    float w2 = vW[(k4 + 2) * 128 + c], w3 = vW[(k4 + 3) * 128 + c];
#pragma unroll
    for (int r = 0; r < 8; ++r) {
      float4 x = *(const float4*)&in[r][k4];
      acc[r] += x.x * w0 + x.y * w1 + x.z * w2 + x.w * w3;
    }
  }
#pragma unroll
  for (int r = 0; r < 8; ++r) {
    float val = fmaxf(acc[r], 0.f) + in[r][128 + c];  // relu + residual
    outs[r][c] = val;
    v[(r0 + r) * 128 + c] = val;
  }
  __syncthreads();
  if (c < 8) {  // per-(b,n) partial sums for BN stats over (B,D)
    float s = 0.f, s2 = 0.f;
    for (int k = 0; k < 128; ++k) { float x = outs[c][k]; s += x; s2 += x * x; }
    int n = (r0 + c) & 63;
    atomicAdd(&stats[n], s);
    atomicAdd(&stats[64 + n], s2);
  }
}

// ------------- g3 final: per-b block. BN(v), ev3, out_e = edot+eb3+ev3_i+ev3_j,
// pve3 in LDS, out_v. One kernel, 64 blocks. -------------
__global__ __launch_bounds__(256) void k_g3(const float* __restrict__ vv,
    const float* __restrict__ stats3, const float* __restrict__ g,
    const float* __restrict__ bt, const float* __restrict__ evW3,
    const float* __restrict__ evb3, const float* __restrict__ eb3,
    const float* __restrict__ edt, const float* __restrict__ vW3,
    const float* __restrict__ vb3, float* __restrict__ out_v,
    float* __restrict__ out_e) {
  __shared__ float vbn[64][132];   // +4 pad
  __shared__ float edts[64][68];   // edt[b][j][i], +4 pad (16B-aligned rows)
  __shared__ float scs[64], shs[64];
  __shared__ float W3e[128];
  __shared__ float vWs[132];
  __shared__ float ev3s[64];
  __shared__ float pj[4][64];
  const int b = blockIdx.x, tid = threadIdx.x;
  if (tid < 64) {
    float mu = stats3[tid] * (1.f / 8192.f);
    float var = stats3[64 + tid] * (1.f / 8192.f) - mu * mu;
    float sc = rsqrtf(var + 128.f) * g[tid];
    scs[tid] = sc;
    shs[tid] = bt[tid] - mu * sc;
  }
  if (tid < 128) W3e[tid] = evW3[tid];
  if (tid < 129) vWs[tid] = vW3[tid];
  __syncthreads();
#pragma unroll
  for (int t = 0; t < 8; ++t) {  // stage BN(v[b])
    int idx = t * 1024 + tid * 4;
    int row = idx >> 7, cc = idx & 127;
    f32x4 x = *(const f32x4*)&vv[(b * 64 + row) * 128 + cc];
    *(f32x4*)&vbn[row][cc] = x * scs[row] + shs[row];
  }
#pragma unroll
  for (int t = 0; t < 4; ++t) {  // stage edot[b]
    int idx = t * 1024 + tid * 4;
    int j = idx >> 6, i = idx & 63;
    *(f32x4*)&edts[j][i] = *(const f32x4*)&edt[(b * 64 + j) * 64 + i];
  }
  __syncthreads();
  {  // ev3s[i] = dot(vbn[i], W3e) + evb3
    int i = tid >> 2, q = tid & 3;
    float d = 0.f;
#pragma unroll
    for (int u = 0; u < 32; ++u) d += vbn[i][q * 32 + u] * W3e[q * 32 + u];
    d += __shfl_xor(d, 1);
    d += __shfl_xor(d, 2);
    if (q == 0) ev3s[i] = d + evb3[0];
  }
  __syncthreads();
  {  // out_e + per-j partial sums
    int q = tid >> 6, j = tid & 63;
    float s = 0.f;
    const float e3 = eb3[0];
    const float evj = ev3s[j];
#pragma unroll
    for (int r = 0; r < 16; ++r) {
      int i = q * 16 + r;
      float val = edts[j][i] + e3 + ev3s[i] + evj;
      out_e[(b * 64 + i) * 64 + j] = val;
      s += val;
    }
    pj[q][j] = s;
  }
  __syncthreads();
  {  // out_v[b,n] = pve3*vW[0] + dot(vbn[n], vW[1:129]) + vb
    int n = tid >> 2, q = tid & 3;
    float d = 0.f;
#pragma unroll
    for (int u = 0; u < 32; ++u) d += vbn[n][q * 32 + u] * vWs[1 + q * 32 + u];
    d += __shfl_xor(d, 1);
    d += __shfl_xor(d, 2);
    if (q == 0) {
      float p3 = pj[0][n] + pj[1][n] + pj[2][n] + pj[3][n];
      out_v[b * 64 + n] = d + p3 * vWs[0] + vb3[0];
    }
  }
}

extern "C" void kernel_launch(void* const* d_in, const int* in_sizes, int n_in,
                              void* d_out, int out_size, void* d_ws, size_t ws_size,
                              hipStream_t stream) {
  const float* in_v    = (const float*)d_in[0];
  const float* in_e    = (const float*)d_in[1];
  const float* bn_in_g = (const float*)d_in[2];
  const float* bn_in_b = (const float*)d_in[3];
  const float* g1_evW  = (const float*)d_in[4];
  const float* g1_evb  = (const float*)d_in[5];
  const float* g1_eW   = (const float*)d_in[6];
  const float* g1_eb   = (const float*)d_in[7];
  const float* g1_vW   = (const float*)d_in[8];
  const float* g1_vb   = (const float*)d_in[9];
  const float* inn_evW = (const float*)d_in[10];
  const float* inn_evb = (const float*)d_in[11];
  const float* inn_eW  = (const float*)d_in[12];
  const float* inn_eb  = (const float*)d_in[13];
  const float* inn_vW  = (const float*)d_in[14];
  const float* inn_vb  = (const float*)d_in[15];
  const float* bn_g    = (const float*)d_in[16];
  const float* bn_b    = (const float*)d_in[17];
  const float* g3_evW  = (const float*)d_in[18];
  const float* g3_evb  = (const float*)d_in[19];
  const float* g3_eW   = (const float*)d_in[20];
  const float* g3_eb   = (const float*)d_in[21];
  const float* g3_vW   = (const float*)d_in[22];
  const float* g3_vb   = (const float*)d_in[23];

  char* ws = (char*)d_ws;
  bf16_t* e_ws = (bf16_t*)(ws);                       // 64MB : e as bf16
  float* v     = (float*)(ws + 67108864);             // 2MB
  float* ev    = (float*)(ws + 69206016);             // 2MB
  float* pve   = (float*)(ws + 71303168);             // 2MB
  float* v0    = (float*)(ws + 73400320);             // 512KB
  bf16_t* Wt   = (bf16_t*)(ws + 73924608);            // 128KB
  float* edt   = (float*)(ws + 74055680);             // 1MB : edot[b][j][i]
  float* stats = (float*)(ws + 75104256);             // 2KB (4 layers x 128 f32)

  float* out_v = (float*)d_out;          // [B,N,1] = 4096
  float* out_e = (float*)d_out + 4096;   // [B,N,N,1] = 262144

  k_prep<<<265, 256, 0, stream>>>(in_v, bn_in_g, bn_in_b, inn_eW, v0, Wt, stats);

  // ---- g1 ----
  k_ev<32><<<512, 128, 0, stream>>>(v0, g1_evW, g1_evb, ev);
  k_edge_g1<<<2048, 256, 0, stream>>>(in_e, g1_eW, g1_eb, ev, e_ws, pve);
  k_vg1_ev<<<512, 128, 0, stream>>>(pve, v0, g1_vW, g1_vb, inn_evW, inn_evb, v, ev);

  // ---- inner layers ----
  for (int l = 0; l < 4; ++l) {
    if (l > 0)
      k_evbn<<<512, 128, 0, stream>>>(v, stats + (l - 1) * 128, bn_g + (l - 1) * 64,
                                      bn_b + (l - 1) * 64, inn_evW + l * 16384,
                                      inn_evb + l * 128, ev);
    if (l < 3)
      k_edge_inner<false><<<1024, 256, 0, stream>>>(e_ws, Wt + l * 16384,
          inn_eb + l * 128, ev, pve, g3_eW, edt);
    else
      k_edge_inner<true><<<1024, 256, 0, stream>>>(e_ws, Wt + l * 16384,
          inn_eb + l * 128, ev, pve, g3_eW, edt);
    k_v_inner<<<512, 128, 0, stream>>>(pve, v, inn_vW + l * 32768, inn_vb + l * 128,
                                       stats + l * 128);
  }

  // ---- g3 final (BN of layer 3 on the fly; pve3 in-block) ----
  k_g3<<<64, 256, 0, stream>>>(v, stats + 384, bn_g + 192, bn_b + 192,
                               g3_evW, g3_evb, g3_eb, edt, g3_vW, g3_vb,
                               out_v, out_e);
}

// Round 7
// 368.823 us; speedup vs baseline: 1.4423x; 1.2340x over previous
//
#include <hip/hip_runtime.h>
#include <hip/hip_bf16.h>

// GraphVertEdgeNet on MI355X. B=64, N=64, VF=32, EF=16, DV=DE=128, LN=4.
// e stored bf16 in ws (64MB). Inner edge: non-persistent 2048 blocks x 2 cols
// (R3 structure - best WRITE_SIZE), lgkm-only barriers, layer-3 fuses the g3
// edge dot and skips e write-back. All small GEMM kernels: 256-thread blocks
// (2 waves/SIMD) - R6's 128-thread/1-wave-per-SIMD versions were latency-bound.

typedef __bf16 bf16_t;
typedef __bf16 bf16x8 __attribute__((ext_vector_type(8)));
typedef __bf16 bf16x4 __attribute__((ext_vector_type(4)));
typedef float f32x4 __attribute__((ext_vector_type(4)));

// Barrier that does NOT drain vmcnt: safe when cross-wave deps are LDS-only.
__device__ __forceinline__ void bar_lgkm() {
  asm volatile("s_waitcnt lgkmcnt(0)\n\ts_barrier" ::: "memory");
}

// ---------------- prep: input BN (v0), Wt transpose, zero stats ----------------
__global__ __launch_bounds__(256) void k_prep(const float* __restrict__ vin,
    const float* __restrict__ g, const float* __restrict__ bt,
    const float* __restrict__ eW, float* __restrict__ v0,
    bf16_t* __restrict__ Wt, float* __restrict__ stats) {
  const int blk = blockIdx.x, tid = threadIdx.x;
  if (blk < 8) {  // BatchNorm1d(N*VF) over batch, ch = 0..2047
    int ch = blk * 256 + tid;
    float s = 0.f, s2 = 0.f;
    for (int b = 0; b < 64; ++b) { float x = vin[b * 2048 + ch]; s += x; s2 += x * x; }
    float mu = s * (1.f / 64.f);
    float var = s2 * (1.f / 64.f) - mu * mu;  // biased var
    float sc = rsqrtf(var + 1e-5f) * g[ch];
    float bb = bt[ch];
    for (int b = 0; b < 64; ++b) {
      float x = vin[b * 2048 + ch];
      v0[b * 2048 + ch] = (x - mu) * sc + bb;
    }
  } else if (blk < 264) {  // Wt[l][n][k] = eW[l][k][n] as bf16
    int idx = (blk - 8) * 256 + tid;  // 4*128*128 = 65536
    int l = idx >> 14, r = idx & 16383, n = r >> 7, k = r & 127;
    Wt[idx] = (bf16_t)eW[(l << 14) + (k << 7) + n];
  } else {  // zero stats (512 f32)
    for (int i = tid; i < 512; i += 256) stats[i] = 0.f;
  }
}

// ------------- ev = v_in @ W + bias : [4096,K]@[K,128]. 256 thr, 8 rows/blk -------------
template <int K>
__global__ __launch_bounds__(256) void k_ev(const float* __restrict__ v_in,
    const float* __restrict__ W, const float* __restrict__ bias,
    float* __restrict__ out) {
  __shared__ float rows_s[8][K];
  const int r0 = blockIdx.x * 8;
  const int tid = threadIdx.x;
  const int c = tid & 127, h = tid >> 7;  // h: rows h*4 .. h*4+3
  for (int idx = tid; idx < 8 * K; idx += 256) {
    int rr = idx / K, kk = idx % K;
    rows_s[rr][kk] = v_in[(r0 + rr) * K + kk];
  }
  __syncthreads();
  float acc[4];
  const float bv = bias[c];
#pragma unroll
  for (int r = 0; r < 4; ++r) acc[r] = bv;
  for (int k4 = 0; k4 < K; k4 += 4) {
    float w0 = W[(k4 + 0) * 128 + c], w1 = W[(k4 + 1) * 128 + c];
    float w2 = W[(k4 + 2) * 128 + c], w3 = W[(k4 + 3) * 128 + c];
#pragma unroll
    for (int r = 0; r < 4; ++r) {
      float4 x = *(const float4*)&rows_s[h * 4 + r][k4];
      acc[r] += x.x * w0 + x.y * w1 + x.z * w2 + x.w * w3;
    }
  }
#pragma unroll
  for (int r = 0; r < 4; ++r) out[(r0 + h * 4 + r) * 128 + c] = acc[r];
}

// ------------- fused BN(prev) + ev matmul (in-place v normalize). 256 thr -------------
__global__ __launch_bounds__(256) void k_evbn(float* __restrict__ v,
    const float* __restrict__ stats, const float* __restrict__ g,
    const float* __restrict__ bt, const float* __restrict__ W,
    const float* __restrict__ bias, float* __restrict__ out) {
  __shared__ float rows_s[8][128];
  const int r0 = blockIdx.x * 8;
  const int tid = threadIdx.x;
  const int c = tid & 127, h = tid >> 7;
#pragma unroll
  for (int u = 0; u < 4; ++u) {
    int idx = u * 256 + tid;
    int rr = idx >> 7, k = idx & 127;
    int n = (r0 + rr) & 63;
    float mu = stats[n] * (1.f / 8192.f);
    float var = stats[64 + n] * (1.f / 8192.f) - mu * mu;
    float sc = rsqrtf(var + 128.f) * g[n];
    float x = (v[(r0 + rr) * 128 + k] - mu) * sc + bt[n];
    rows_s[rr][k] = x;
    v[(r0 + rr) * 128 + k] = x;  // normalized v for residual/concat
  }
  __syncthreads();
  float acc[4];
  const float bv = bias[c];
#pragma unroll
  for (int r = 0; r < 4; ++r) acc[r] = bv;
  for (int k4 = 0; k4 < 128; k4 += 4) {
    float w0 = W[(k4 + 0) * 128 + c], w1 = W[(k4 + 1) * 128 + c];
    float w2 = W[(k4 + 2) * 128 + c], w3 = W[(k4 + 3) * 128 + c];
#pragma unroll
    for (int r = 0; r < 4; ++r) {
      float4 x = *(const float4*)&rows_s[h * 4 + r][k4];
      acc[r] += x.x * w0 + x.y * w1 + x.z * w2 + x.w * w3;
    }
  }
#pragma unroll
  for (int r = 0; r < 4; ++r) out[(r0 + h * 4 + r) * 128 + c] = acc[r];
}

// ------------- g1 edge pass (MFMA, K 16->32 zero-pad, 2 j/block) -------------
__global__ __launch_bounds__(256) void k_edge_g1(const float* __restrict__ e0,
    const float* __restrict__ eW, const float* __restrict__ eb,
    const float* __restrict__ ev, bf16_t* __restrict__ e_ws,
    float* __restrict__ pve) {
  __shared__ bf16_t A0s[2][64][40];
  __shared__ bf16_t Os[2][64][136];
  const int b = blockIdx.x >> 5, j0 = (blockIdx.x & 31) * 2;
  const int tid = threadIdx.x;
  const int lane = tid & 63, w = tid >> 6;
  const int quad = lane >> 4, l16 = lane & 15;
#pragma unroll
  for (int t = 0; t < 2; ++t) {
    int idx = tid + t * 256;
    int row = idx >> 3, off = (idx & 7) * 4;
    int jc = off >> 4, k = off & 15;
    f32x4 x = *(const f32x4*)&e0[((b * 64 + row) * 64 + j0) * 16 + off];
    bf16x4 y;
#pragma unroll
    for (int r = 0; r < 4; ++r) y[r] = (bf16_t)x[r];
    *(bf16x4*)&A0s[jc][row][k] = y;
    bf16x4 z = {(bf16_t)0.f, (bf16_t)0.f, (bf16_t)0.f, (bf16_t)0.f};
    *(bf16x4*)&A0s[jc][row][16 + k] = z;
  }
  const int c0[2] = {w * 32 + quad * 4, w * 32 + 16 + quad * 4};
  bf16x8 wf[2];
#pragma unroll
  for (int nt = 0; nt < 2; ++nt) {
    const int c = w * 32 + nt * 16 + l16;
#pragma unroll
    for (int jj = 0; jj < 8; ++jj)
      wf[nt][jj] = (quad < 2) ? (bf16_t)eW[(quad * 8 + jj) * 128 + c] : (bf16_t)0.f;
  }
  f32x4 acc[2][4][2];
  {
    f32x4 ebv[2], evj[2][2], evi[4][2];
#pragma unroll
    for (int nt = 0; nt < 2; ++nt) {
      ebv[nt] = *(const f32x4*)&eb[c0[nt]];
#pragma unroll
      for (int jc = 0; jc < 2; ++jc)
        evj[jc][nt] = *(const f32x4*)&ev[(b * 64 + j0 + jc) * 128 + c0[nt]];
#pragma unroll
      for (int mt = 0; mt < 4; ++mt)
        evi[mt][nt] = *(const f32x4*)&ev[(b * 64 + mt * 16 + l16) * 128 + c0[nt]];
    }
#pragma unroll
    for (int jc = 0; jc < 2; ++jc)
#pragma unroll
      for (int mt = 0; mt < 4; ++mt)
#pragma unroll
        for (int nt = 0; nt < 2; ++nt)
          acc[jc][mt][nt] = ebv[nt] + evj[jc][nt] + evi[mt][nt];
  }
  __syncthreads();
#pragma unroll
  for (int jc = 0; jc < 2; ++jc) {
#pragma unroll
    for (int mt = 0; mt < 4; ++mt) {
      bf16x8 ef = *(const bf16x8*)&A0s[jc][mt * 16 + l16][quad * 8];
#pragma unroll
      for (int nt = 0; nt < 2; ++nt)
        acc[jc][mt][nt] = __builtin_amdgcn_mfma_f32_16x16x32_bf16(wf[nt], ef, acc[jc][mt][nt], 0, 0, 0);
    }
  }
#pragma unroll
  for (int jc = 0; jc < 2; ++jc) {
#pragma unroll
    for (int nt = 0; nt < 2; ++nt) {
      f32x4 ps = {0.f, 0.f, 0.f, 0.f};
#pragma unroll
      for (int mt = 0; mt < 4; ++mt) {
        const int i = mt * 16 + l16;
        bf16x4 outv;
#pragma unroll
        for (int r = 0; r < 4; ++r) {
          float vv = fmaxf(acc[jc][mt][nt][r], 0.f);
          ps[r] += vv;
          outv[r] = (bf16_t)vv;
        }
        *(bf16x4*)&Os[jc][i][c0[nt]] = outv;
      }
#pragma unroll
      for (int m = 1; m <= 8; m <<= 1) {
#pragma unroll
        for (int r = 0; r < 4; ++r) ps[r] += __shfl_xor(ps[r], m);
      }
      if (l16 == 0) *(f32x4*)&pve[(b * 64 + j0 + jc) * 128 + c0[nt]] = ps;
    }
  }
  __syncthreads();
#pragma unroll
  for (int t = 0; t < 8; ++t) {
    int idx = tid + t * 256;
    int row = idx >> 5, off = (idx & 31) * 8;
    int jc = off >> 7, c = off & 127;
    *(int4*)&e_ws[((b * 64 + row) * 64 + j0) * 128 + off] = *(const int4*)&Os[jc][row][c];
  }
}

// ------------- fused g1-v + layer0-ev. 256 thr, 8 rows/blk -------------
__global__ __launch_bounds__(256) void k_vg1_ev(const float* __restrict__ pve,
    const float* __restrict__ v0, const float* __restrict__ vW,
    const float* __restrict__ vb, const float* __restrict__ evW,
    const float* __restrict__ evb, float* __restrict__ v, float* __restrict__ ev) {
  __shared__ float in_s[8][160];
  __shared__ float vr[8][128];
  const int r0 = blockIdx.x * 8;
  const int tid = threadIdx.x;
  const int c = tid & 127, h = tid >> 7;
#pragma unroll
  for (int u = 0; u < 4; ++u) {
    int idx = u * 256 + tid;
    int rr = idx >> 7, k = idx & 127;
    in_s[rr][k] = pve[(r0 + rr) * 128 + k];
  }
  {
    int rr = tid >> 5, k = tid & 31;
    in_s[rr][128 + k] = v0[(r0 + rr) * 32 + k];
  }
  __syncthreads();
  float acc[4];
  const float bv = vb[c];
#pragma unroll
  for (int r = 0; r < 4; ++r) acc[r] = bv;
  for (int k4 = 0; k4 < 160; k4 += 4) {
    float w0 = vW[(k4 + 0) * 128 + c], w1 = vW[(k4 + 1) * 128 + c];
    float w2 = vW[(k4 + 2) * 128 + c], w3 = vW[(k4 + 3) * 128 + c];
#pragma unroll
    for (int r = 0; r < 4; ++r) {
      float4 x = *(const float4*)&in_s[h * 4 + r][k4];
      acc[r] += x.x * w0 + x.y * w1 + x.z * w2 + x.w * w3;
    }
  }
#pragma unroll
  for (int r = 0; r < 4; ++r) {
    float val = fmaxf(acc[r], 0.f);
    vr[h * 4 + r][c] = val;
    v[(r0 + h * 4 + r) * 128 + c] = val;
  }
  __syncthreads();
  float acc2[4];
  const float bv2 = evb[c];
#pragma unroll
  for (int r = 0; r < 4; ++r) acc2[r] = bv2;
  for (int k4 = 0; k4 < 128; k4 += 4) {
    float w0 = evW[(k4 + 0) * 128 + c], w1 = evW[(k4 + 1) * 128 + c];
    float w2 = evW[(k4 + 2) * 128 + c], w3 = evW[(k4 + 3) * 128 + c];
#pragma unroll
    for (int r = 0; r < 4; ++r) {
      float4 x = *(const float4*)&vr[h * 4 + r][k4];
      acc2[r] += x.x * w0 + x.y * w1 + x.z * w2 + x.w * w3;
    }
  }
#pragma unroll
  for (int r = 0; r < 4; ++r) ev[(r0 + h * 4 + r) * 128 + c] = acc2[r];
}

// ------------- inner edge pass: non-persistent 2048 blocks x 2 cols, lgkm barriers -------------
// e += relu(e@W + eb + ev_i + ev_j); pve = per-column sum of pre-residual.
// LAST: instead of e write-back, computes edot[b][j][i] = dot(e_new[b,i,j,:], eW3).
template <bool LAST>
__global__ __launch_bounds__(256) void k_edge_inner(bf16_t* __restrict__ e_ws,
    const bf16_t* __restrict__ Wt, const float* __restrict__ eb,
    const float* __restrict__ ev, float* __restrict__ pve,
    const float* __restrict__ eW3, float* __restrict__ edt) {
  __shared__ bf16_t As[2][64][136];   // [jc][row][col], +8 pad
  __shared__ float W3s[128];
  const int b = blockIdx.x >> 5, j0 = (blockIdx.x & 31) * 2;
  const int tid = threadIdx.x;
  const int lane = tid & 63, w = tid >> 6;
  const int quad = lane >> 4, l16 = lane & 15;
  // stage 2 e columns: 512B contiguous per row
  int4 stg[8];
#pragma unroll
  for (int t = 0; t < 8; ++t) {
    int idx = tid + t * 256;
    int row = idx >> 5, off = (idx & 31) * 8;
    stg[t] = *(const int4*)&e_ws[((b * 64 + row) * 64 + j0) * 128 + off];
  }
  if (LAST) {
    if (tid < 128) W3s[tid] = eW3[tid];
  }
  // W A-frags in registers (L2-hot): A[m=c][k]
  bf16x8 wf[2][4];
#pragma unroll
  for (int nt = 0; nt < 2; ++nt)
#pragma unroll
    for (int ks = 0; ks < 4; ++ks)
      wf[nt][ks] = *(const bf16x8*)&Wt[(w * 32 + nt * 16 + l16) * 128 + ks * 32 + quad * 8];
  const int c0[2] = {w * 32 + quad * 4, w * 32 + 16 + quad * 4};
  // acc init = eb + ev_j + ev_i (pre-barrier loads)
  f32x4 acc[2][4][2];
  {
    f32x4 ebv[2], evj[2][2], evi[4][2];
#pragma unroll
    for (int nt = 0; nt < 2; ++nt) {
      ebv[nt] = *(const f32x4*)&eb[c0[nt]];
#pragma unroll
      for (int jc = 0; jc < 2; ++jc)
        evj[jc][nt] = *(const f32x4*)&ev[(b * 64 + j0 + jc) * 128 + c0[nt]];
#pragma unroll
      for (int mt = 0; mt < 4; ++mt)
        evi[mt][nt] = *(const f32x4*)&ev[(b * 64 + mt * 16 + l16) * 128 + c0[nt]];
    }
#pragma unroll
    for (int jc = 0; jc < 2; ++jc)
#pragma unroll
      for (int mt = 0; mt < 4; ++mt)
#pragma unroll
        for (int nt = 0; nt < 2; ++nt)
          acc[jc][mt][nt] = ebv[nt] + evj[jc][nt] + evi[mt][nt];
  }
#pragma unroll
  for (int t = 0; t < 8; ++t) {
    int idx = tid + t * 256;
    int row = idx >> 5, off = (idx & 31) * 8;
    *(int4*)&As[off >> 7][row][off & 127] = stg[t];
  }
  bar_lgkm();
  // MFMA: D[c][i] = sum_k Wt[c][k] * e[i][k]  (64 MFMA per block)
#pragma unroll
  for (int ks = 0; ks < 4; ++ks) {
    bf16x8 ef[2][4];
#pragma unroll
    for (int jc = 0; jc < 2; ++jc)
#pragma unroll
      for (int mt = 0; mt < 4; ++mt)
        ef[jc][mt] = *(const bf16x8*)&As[jc][mt * 16 + l16][ks * 32 + quad * 8];
#pragma unroll
    for (int jc = 0; jc < 2; ++jc)
#pragma unroll
      for (int mt = 0; mt < 4; ++mt)
#pragma unroll
        for (int nt = 0; nt < 2; ++nt)
          acc[jc][mt][nt] = __builtin_amdgcn_mfma_f32_16x16x32_bf16(wf[nt][ks], ef[jc][mt], acc[jc][mt][nt], 0, 0, 0);
  }
  bar_lgkm();  // all MFMA frag reads of As done (LDS-only dep)
  // epilogue: relu, pve, residual from LDS, packed b64 writes to own cells
#pragma unroll
  for (int jc = 0; jc < 2; ++jc) {
#pragma unroll
    for (int nt = 0; nt < 2; ++nt) {
      f32x4 ps = {0.f, 0.f, 0.f, 0.f};
#pragma unroll
      for (int mt = 0; mt < 4; ++mt) {
        const int i = mt * 16 + l16;
        bf16x4 eo = *(const bf16x4*)&As[jc][i][c0[nt]];
        bf16x4 outv;
#pragma unroll
        for (int r = 0; r < 4; ++r) {
          float vv = fmaxf(acc[jc][mt][nt][r], 0.f);
          ps[r] += vv;                            // pve is pre-residual
          outv[r] = (bf16_t)(vv + (float)eo[r]);  // residual
        }
        *(bf16x4*)&As[jc][i][c0[nt]] = outv;
      }
#pragma unroll
      for (int m = 1; m <= 8; m <<= 1) {  // reduce over i (l16 lanes)
#pragma unroll
        for (int r = 0; r < 4; ++r) ps[r] += __shfl_xor(ps[r], m);
      }
      if (l16 == 0) *(f32x4*)&pve[(b * 64 + j0 + jc) * 128 + c0[nt]] = ps;
    }
  }
  bar_lgkm();  // As fully updated (LDS-only dep)
  if (!LAST) {
    // coalesced e write-back: 512B per row
#pragma unroll
    for (int t = 0; t < 8; ++t) {
      int idx = tid + t * 256;
      int row = idx >> 5, off = (idx & 31) * 8;
      *(int4*)&e_ws[((b * 64 + row) * 64 + j0) * 128 + off] =
          *(const int4*)&As[off >> 7][row][off & 127];
    }
  } else {
    // edot[b][j][i] = dot(e_new[b,i,j,:], W3)
    const int i = tid >> 2, q = tid & 3;
#pragma unroll
    for (int jc = 0; jc < 2; ++jc) {
      float d = 0.f;
#pragma unroll
      for (int t = 0; t < 4; ++t) {
        bf16x8 x = *(const bf16x8*)&As[jc][i][q * 32 + t * 8];
#pragma unroll
        for (int u = 0; u < 8; ++u) d += (float)x[u] * W3s[q * 32 + t * 8 + u];
      }
      d += __shfl_xor(d, 1);
      d += __shfl_xor(d, 2);
      if (q == 0) edt[(b * 64 + j0 + jc) * 64 + i] = d;
    }
  }
}

// ------------- inner v pass: v = relu(concat(pve,v)@[256,128]+vb) + v; BN stats. 256 thr -------------
__global__ __launch_bounds__(256) void k_v_inner(const float* __restrict__ pve,
    float* __restrict__ v, const float* __restrict__ vW,
    const float* __restrict__ vb, float* __restrict__ stats) {
  __shared__ float in_s[8][256];
  __shared__ float outs[8][132];  // +4 pad
  __shared__ float part[16][2];
  const int r0 = blockIdx.x * 8;
  const int tid = threadIdx.x;
  const int c = tid & 127, h = tid >> 7;
#pragma unroll
  for (int u = 0; u < 4; ++u) {
    int idx = u * 256 + tid;
    int rr = idx >> 7, k = idx & 127;
    in_s[rr][k] = pve[(r0 + rr) * 128 + k];
    in_s[rr][128 + k] = v[(r0 + rr) * 128 + k];
  }
  __syncthreads();
  float acc[4];
  const float bv = vb[c];
#pragma unroll
  for (int r = 0; r < 4; ++r) acc[r] = bv;
  for (int k4 = 0; k4 < 256; k4 += 4) {
    float w0 = vW[(k4 + 0) * 128 + c], w1 = vW[(k4 + 1) * 128 + c];
    float w2 = vW[(k4 + 2) * 128 + c], w3 = vW[(k4 + 3) * 128 + c];
#pragma unroll
    for (int r = 0; r < 4; ++r) {
      float4 x = *(const float4*)&in_s[h * 4 + r][k4];
      acc[r] += x.x * w0 + x.y * w1 + x.z * w2 + x.w * w3;
    }
  }
#pragma unroll
  for (int r = 0; r < 4; ++r) {
    float val = fmaxf(acc[r], 0.f) + in_s[h * 4 + r][128 + c];  // relu + residual
    outs[h * 4 + r][c] = val;
    v[(r0 + h * 4 + r) * 128 + c] = val;
  }
  __syncthreads();
  if (tid < 16) {  // parallel BN-stat partial reduction
    int rr = tid >> 1, half = tid & 1;
    float s = 0.f, s2 = 0.f;
    for (int k = 0; k < 64; ++k) {
      float x = outs[rr][half * 64 + k];
      s += x; s2 += x * x;
    }
    part[tid][0] = s;
    part[tid][1] = s2;
  }
  __syncthreads();
  if (tid < 8) {
    int n = (r0 + tid) & 63;
    atomicAdd(&stats[n], part[tid * 2][0] + part[tid * 2 + 1][0]);
    atomicAdd(&stats[64 + n], part[tid * 2][1] + part[tid * 2 + 1][1]);
  }
}

// ------------- g3 final: per-b block. BN(v), ev3, out_e = edot+eb3+ev3_i+ev3_j,
// pve3 in LDS, out_v. One kernel, 64 blocks. -------------
__global__ __launch_bounds__(256) void k_g3(const float* __restrict__ vv,
    const float* __restrict__ stats3, const float* __restrict__ g,
    const float* __restrict__ bt, const float* __restrict__ evW3,
    const float* __restrict__ evb3, const float* __restrict__ eb3,
    const float* __restrict__ edt, const float* __restrict__ vW3,
    const float* __restrict__ vb3, float* __restrict__ out_v,
    float* __restrict__ out_e) {
  __shared__ float vbn[64][132];   // +4 pad
  __shared__ float edts[64][68];   // edt[b][j][i], +4 pad
  __shared__ float scs[64], shs[64];
  __shared__ float W3e[128];
  __shared__ float vWs[132];
  __shared__ float ev3s[64];
  __shared__ float pj[4][64];
  const int b = blockIdx.x, tid = threadIdx.x;
  if (tid < 64) {
    float mu = stats3[tid] * (1.f / 8192.f);
    float var = stats3[64 + tid] * (1.f / 8192.f) - mu * mu;
    float sc = rsqrtf(var + 128.f) * g[tid];
    scs[tid] = sc;
    shs[tid] = bt[tid] - mu * sc;
  }
  if (tid < 128) W3e[tid] = evW3[tid];
  if (tid < 129) vWs[tid] = vW3[tid];
  __syncthreads();
#pragma unroll
  for (int t = 0; t < 8; ++t) {  // stage BN(v[b])
    int idx = t * 1024 + tid * 4;
    int row = idx >> 7, cc = idx & 127;
    f32x4 x = *(const f32x4*)&vv[(b * 64 + row) * 128 + cc];
    *(f32x4*)&vbn[row][cc] = x * scs[row] + shs[row];
  }
#pragma unroll
  for (int t = 0; t < 4; ++t) {  // stage edot[b]
    int idx = t * 1024 + tid * 4;
    int j = idx >> 6, i = idx & 63;
    *(f32x4*)&edts[j][i] = *(const f32x4*)&edt[(b * 64 + j) * 64 + i];
  }
  __syncthreads();
  {  // ev3s[i] = dot(vbn[i], W3e) + evb3
    int i = tid >> 2, q = tid & 3;
    float d = 0.f;
#pragma unroll
    for (int u = 0; u < 32; ++u) d += vbn[i][q * 32 + u] * W3e[q * 32 + u];
    d += __shfl_xor(d, 1);
    d += __shfl_xor(d, 2);
    if (q == 0) ev3s[i] = d + evb3[0];
  }
  __syncthreads();
  {  // out_e + per-j partial sums
    int q = tid >> 6, j = tid & 63;
    float s = 0.f;
    const float e3 = eb3[0];
    const float evj = ev3s[j];
#pragma unroll
    for (int r = 0; r < 16; ++r) {
      int i = q * 16 + r;
      float val = edts[j][i] + e3 + ev3s[i] + evj;
      out_e[(b * 64 + i) * 64 + j] = val;
      s += val;
    }
    pj[q][j] = s;
  }
  __syncthreads();
  {  // out_v[b,n] = pve3*vW[0] + dot(vbn[n], vW[1:129]) + vb
    int n = tid >> 2, q = tid & 3;
    float d = 0.f;
#pragma unroll
    for (int u = 0; u < 32; ++u) d += vbn[n][q * 32 + u] * vWs[1 + q * 32 + u];
    d += __shfl_xor(d, 1);
    d += __shfl_xor(d, 2);
    if (q == 0) {
      float p3 = pj[0][n] + pj[1][n] + pj[2][n] + pj[3][n];
      out_v[b * 64 + n] = d + p3 * vWs[0] + vb3[0];
    }
  }
}

extern "C" void kernel_launch(void* const* d_in, const int* in_sizes, int n_in,
                              void* d_out, int out_size, void* d_ws, size_t ws_size,
                              hipStream_t stream) {
  const float* in_v    = (const float*)d_in[0];
  const float* in_e    = (const float*)d_in[1];
  const float* bn_in_g = (const float*)d_in[2];
  const float* bn_in_b = (const float*)d_in[3];
  const float* g1_evW  = (const float*)d_in[4];
  const float* g1_evb  = (const float*)d_in[5];
  const float* g1_eW   = (const float*)d_in[6];
  const float* g1_eb   = (const float*)d_in[7];
  const float* g1_vW   = (const float*)d_in[8];
  const float* g1_vb   = (const float*)d_in[9];
  const float* inn_evW = (const float*)d_in[10];
  const float* inn_evb = (const float*)d_in[11];
  const float* inn_eW  = (const float*)d_in[12];
  const float* inn_eb  = (const float*)d_in[13];
  const float* inn_vW  = (const float*)d_in[14];
  const float* inn_vb  = (const float*)d_in[15];
  const float* bn_g    = (const float*)d_in[16];
  const float* bn_b    = (const float*)d_in[17];
  const float* g3_evW  = (const float*)d_in[18];
  const float* g3_evb  = (const float*)d_in[19];
  const float* g3_eW   = (const float*)d_in[20];
  const float* g3_eb   = (const float*)d_in[21];
  const float* g3_vW   = (const float*)d_in[22];
  const float* g3_vb   = (const float*)d_in[23];

  char* ws = (char*)d_ws;
  bf16_t* e_ws = (bf16_t*)(ws);                       // 64MB : e as bf16
  float* v     = (float*)(ws + 67108864);             // 2MB
  float* ev    = (float*)(ws + 69206016);             // 2MB
  float* pve   = (float*)(ws + 71303168);             // 2MB
  float* v0    = (float*)(ws + 73400320);             // 512KB
  bf16_t* Wt   = (bf16_t*)(ws + 73924608);            // 128KB
  float* edt   = (float*)(ws + 74055680);             // 1MB : edot[b][j][i]
  float* stats = (float*)(ws + 75104256);             // 2KB (4 layers x 128 f32)

  float* out_v = (float*)d_out;          // [B,N,1] = 4096
  float* out_e = (float*)d_out + 4096;   // [B,N,N,1] = 262144

  k_prep<<<265, 256, 0, stream>>>(in_v, bn_in_g, bn_in_b, inn_eW, v0, Wt, stats);

  // ---- g1 ----
  k_ev<32><<<512, 256, 0, stream>>>(v0, g1_evW, g1_evb, ev);
  k_edge_g1<<<2048, 256, 0, stream>>>(in_e, g1_eW, g1_eb, ev, e_ws, pve);
  k_vg1_ev<<<512, 256, 0, stream>>>(pve, v0, g1_vW, g1_vb, inn_evW, inn_evb, v, ev);

  // ---- inner layers ----
  for (int l = 0; l < 4; ++l) {
    if (l > 0)
      k_evbn<<<512, 256, 0, stream>>>(v, stats + (l - 1) * 128, bn_g + (l - 1) * 64,
                                      bn_b + (l - 1) * 64, inn_evW + l * 16384,
                                      inn_evb + l * 128, ev);
    if (l < 3)
      k_edge_inner<false><<<2048, 256, 0, stream>>>(e_ws, Wt + l * 16384,
          inn_eb + l * 128, ev, pve, g3_eW, edt);
    else
      k_edge_inner<true><<<2048, 256, 0, stream>>>(e_ws, Wt + l * 16384,
          inn_eb + l * 128, ev, pve, g3_eW, edt);
    k_v_inner<<<512, 256, 0, stream>>>(pve, v, inn_vW + l * 32768, inn_vb + l * 128,
                                       stats + l * 128);
  }

  // ---- g3 final (BN of layer 3 on the fly; pve3 in-block) ----
  k_g3<<<64, 256, 0, stream>>>(v, stats + 384, bn_g + 192, bn_b + 192,
                               g3_evW, g3_evb, g3_eb, edt, g3_vW, g3_vb,
                               out_v, out_e);
}

// Round 8
// 366.446 us; speedup vs baseline: 1.4517x; 1.0065x over previous
//
#include <hip/hip_runtime.h>
#include <hip/hip_bf16.h>

// GraphVertEdgeNet on MI355X. B=64, N=64, VF=32, EF=16, DV=DE=128, LN=4.
// e stored bf16 in ws (64MB) in TRANSPOSED layout e_t[b][j][i][c]: every
// consumer accesses e by (b,j)-column across i, so this makes all edge-kernel
// HBM traffic fully contiguous 32KB streams (was 512B chunks @16KB stride).
// Inner edge: non-persistent 2048 blocks x 2 cols, lgkm-only barriers,
// layer-3 fuses the g3 edge dot and skips the e write-back.

typedef __bf16 bf16_t;
typedef __bf16 bf16x8 __attribute__((ext_vector_type(8)));
typedef __bf16 bf16x4 __attribute__((ext_vector_type(4)));
typedef float f32x4 __attribute__((ext_vector_type(4)));

// Barrier that does NOT drain vmcnt: safe when cross-wave deps are LDS-only.
__device__ __forceinline__ void bar_lgkm() {
  asm volatile("s_waitcnt lgkmcnt(0)\n\ts_barrier" ::: "memory");
}

// ---------------- prep: input BN (v0), Wt transpose, zero stats ----------------
__global__ __launch_bounds__(256) void k_prep(const float* __restrict__ vin,
    const float* __restrict__ g, const float* __restrict__ bt,
    const float* __restrict__ eW, float* __restrict__ v0,
    bf16_t* __restrict__ Wt, float* __restrict__ stats) {
  const int blk = blockIdx.x, tid = threadIdx.x;
  if (blk < 8) {  // BatchNorm1d(N*VF) over batch, ch = 0..2047
    int ch = blk * 256 + tid;
    float s = 0.f, s2 = 0.f;
    for (int b = 0; b < 64; ++b) { float x = vin[b * 2048 + ch]; s += x; s2 += x * x; }
    float mu = s * (1.f / 64.f);
    float var = s2 * (1.f / 64.f) - mu * mu;  // biased var
    float sc = rsqrtf(var + 1e-5f) * g[ch];
    float bb = bt[ch];
    for (int b = 0; b < 64; ++b) {
      float x = vin[b * 2048 + ch];
      v0[b * 2048 + ch] = (x - mu) * sc + bb;
    }
  } else if (blk < 264) {  // Wt[l][n][k] = eW[l][k][n] as bf16
    int idx = (blk - 8) * 256 + tid;  // 4*128*128 = 65536
    int l = idx >> 14, r = idx & 16383, n = r >> 7, k = r & 127;
    Wt[idx] = (bf16_t)eW[(l << 14) + (k << 7) + n];
  } else {  // zero stats (512 f32)
    for (int i = tid; i < 512; i += 256) stats[i] = 0.f;
  }
}

// ------------- ev = v_in @ W + bias : [4096,K]@[K,128]. 256 thr, 8 rows/blk -------------
template <int K>
__global__ __launch_bounds__(256) void k_ev(const float* __restrict__ v_in,
    const float* __restrict__ W, const float* __restrict__ bias,
    float* __restrict__ out) {
  __shared__ float rows_s[8][K];
  const int r0 = blockIdx.x * 8;
  const int tid = threadIdx.x;
  const int c = tid & 127, h = tid >> 7;  // h: rows h*4 .. h*4+3
  for (int idx = tid; idx < 8 * K; idx += 256) {
    int rr = idx / K, kk = idx % K;
    rows_s[rr][kk] = v_in[(r0 + rr) * K + kk];
  }
  __syncthreads();
  float acc[4];
  const float bv = bias[c];
#pragma unroll
  for (int r = 0; r < 4; ++r) acc[r] = bv;
  for (int k4 = 0; k4 < K; k4 += 4) {
    float w0 = W[(k4 + 0) * 128 + c], w1 = W[(k4 + 1) * 128 + c];
    float w2 = W[(k4 + 2) * 128 + c], w3 = W[(k4 + 3) * 128 + c];
#pragma unroll
    for (int r = 0; r < 4; ++r) {
      float4 x = *(const float4*)&rows_s[h * 4 + r][k4];
      acc[r] += x.x * w0 + x.y * w1 + x.z * w2 + x.w * w3;
    }
  }
#pragma unroll
  for (int r = 0; r < 4; ++r) out[(r0 + h * 4 + r) * 128 + c] = acc[r];
}

// ------------- fused BN(prev) + ev matmul (in-place v normalize). 256 thr -------------
__global__ __launch_bounds__(256) void k_evbn(float* __restrict__ v,
    const float* __restrict__ stats, const float* __restrict__ g,
    const float* __restrict__ bt, const float* __restrict__ W,
    const float* __restrict__ bias, float* __restrict__ out) {
  __shared__ float rows_s[8][128];
  const int r0 = blockIdx.x * 8;
  const int tid = threadIdx.x;
  const int c = tid & 127, h = tid >> 7;
#pragma unroll
  for (int u = 0; u < 4; ++u) {
    int idx = u * 256 + tid;
    int rr = idx >> 7, k = idx & 127;
    int n = (r0 + rr) & 63;
    float mu = stats[n] * (1.f / 8192.f);
    float var = stats[64 + n] * (1.f / 8192.f) - mu * mu;
    float sc = rsqrtf(var + 128.f) * g[n];
    float x = (v[(r0 + rr) * 128 + k] - mu) * sc + bt[n];
    rows_s[rr][k] = x;
    v[(r0 + rr) * 128 + k] = x;  // normalized v for residual/concat
  }
  __syncthreads();
  float acc[4];
  const float bv = bias[c];
#pragma unroll
  for (int r = 0; r < 4; ++r) acc[r] = bv;
  for (int k4 = 0; k4 < 128; k4 += 4) {
    float w0 = W[(k4 + 0) * 128 + c], w1 = W[(k4 + 1) * 128 + c];
    float w2 = W[(k4 + 2) * 128 + c], w3 = W[(k4 + 3) * 128 + c];
#pragma unroll
    for (int r = 0; r < 4; ++r) {
      float4 x = *(const float4*)&rows_s[h * 4 + r][k4];
      acc[r] += x.x * w0 + x.y * w1 + x.z * w2 + x.w * w3;
    }
  }
#pragma unroll
  for (int r = 0; r < 4; ++r) out[(r0 + h * 4 + r) * 128 + c] = acc[r];
}

// ------------- g1 edge pass (MFMA, K 16->32 zero-pad, 2 j/block) -------------
// Writes e_t[b][j][i][c] (transposed layout): fully contiguous 32KB per block.
__global__ __launch_bounds__(256) void k_edge_g1(const float* __restrict__ e0,
    const float* __restrict__ eW, const float* __restrict__ eb,
    const float* __restrict__ ev, bf16_t* __restrict__ e_ws,
    float* __restrict__ pve) {
  __shared__ bf16_t A0s[2][64][40];
  __shared__ bf16_t Os[2][64][136];
  const int b = blockIdx.x >> 5, j0 = (blockIdx.x & 31) * 2;
  const int tid = threadIdx.x;
  const int lane = tid & 63, w = tid >> 6;
  const int quad = lane >> 4, l16 = lane & 15;
#pragma unroll
  for (int t = 0; t < 2; ++t) {
    int idx = tid + t * 256;
    int row = idx >> 3, off = (idx & 7) * 4;
    int jc = off >> 4, k = off & 15;
    f32x4 x = *(const f32x4*)&e0[((b * 64 + row) * 64 + j0) * 16 + off];
    bf16x4 y;
#pragma unroll
    for (int r = 0; r < 4; ++r) y[r] = (bf16_t)x[r];
    *(bf16x4*)&A0s[jc][row][k] = y;
    bf16x4 z = {(bf16_t)0.f, (bf16_t)0.f, (bf16_t)0.f, (bf16_t)0.f};
    *(bf16x4*)&A0s[jc][row][16 + k] = z;
  }
  const int c0[2] = {w * 32 + quad * 4, w * 32 + 16 + quad * 4};
  bf16x8 wf[2];
#pragma unroll
  for (int nt = 0; nt < 2; ++nt) {
    const int c = w * 32 + nt * 16 + l16;
#pragma unroll
    for (int jj = 0; jj < 8; ++jj)
      wf[nt][jj] = (quad < 2) ? (bf16_t)eW[(quad * 8 + jj) * 128 + c] : (bf16_t)0.f;
  }
  f32x4 acc[2][4][2];
  {
    f32x4 ebv[2], evj[2][2], evi[4][2];
#pragma unroll
    for (int nt = 0; nt < 2; ++nt) {
      ebv[nt] = *(const f32x4*)&eb[c0[nt]];
#pragma unroll
      for (int jc = 0; jc < 2; ++jc)
        evj[jc][nt] = *(const f32x4*)&ev[(b * 64 + j0 + jc) * 128 + c0[nt]];
#pragma unroll
      for (int mt = 0; mt < 4; ++mt)
        evi[mt][nt] = *(const f32x4*)&ev[(b * 64 + mt * 16 + l16) * 128 + c0[nt]];
    }
#pragma unroll
    for (int jc = 0; jc < 2; ++jc)
#pragma unroll
      for (int mt = 0; mt < 4; ++mt)
#pragma unroll
        for (int nt = 0; nt < 2; ++nt)
          acc[jc][mt][nt] = ebv[nt] + evj[jc][nt] + evi[mt][nt];
  }
  __syncthreads();
#pragma unroll
  for (int jc = 0; jc < 2; ++jc) {
#pragma unroll
    for (int mt = 0; mt < 4; ++mt) {
      bf16x8 ef = *(const bf16x8*)&A0s[jc][mt * 16 + l16][quad * 8];
#pragma unroll
      for (int nt = 0; nt < 2; ++nt)
        acc[jc][mt][nt] = __builtin_amdgcn_mfma_f32_16x16x32_bf16(wf[nt], ef, acc[jc][mt][nt], 0, 0, 0);
    }
  }
#pragma unroll
  for (int jc = 0; jc < 2; ++jc) {
#pragma unroll
    for (int nt = 0; nt < 2; ++nt) {
      f32x4 ps = {0.f, 0.f, 0.f, 0.f};
#pragma unroll
      for (int mt = 0; mt < 4; ++mt) {
        const int i = mt * 16 + l16;
        bf16x4 outv;
#pragma unroll
        for (int r = 0; r < 4; ++r) {
          float vv = fmaxf(acc[jc][mt][nt][r], 0.f);
          ps[r] += vv;
          outv[r] = (bf16_t)vv;
        }
        *(bf16x4*)&Os[jc][i][c0[nt]] = outv;
      }
#pragma unroll
      for (int m = 1; m <= 8; m <<= 1) {
#pragma unroll
        for (int r = 0; r < 4; ++r) ps[r] += __shfl_xor(ps[r], m);
      }
      if (l16 == 0) *(f32x4*)&pve[(b * 64 + j0 + jc) * 128 + c0[nt]] = ps;
    }
  }
  __syncthreads();
  {  // contiguous 32KB copy-out to transposed layout
    bf16_t* ebase = &e_ws[((size_t)(b * 64 + j0) * 64) * 128];
#pragma unroll
    for (int t = 0; t < 8; ++t) {
      int idx = tid + t * 256;
      *(int4*)&ebase[idx * 8] =
          *(const int4*)&Os[idx >> 10][(idx >> 4) & 63][(idx & 15) * 8];
    }
  }
}

// ------------- fused g1-v + layer0-ev. 256 thr, 8 rows/blk -------------
__global__ __launch_bounds__(256) void k_vg1_ev(const float* __restrict__ pve,
    const float* __restrict__ v0, const float* __restrict__ vW,
    const float* __restrict__ vb, const float* __restrict__ evW,
    const float* __restrict__ evb, float* __restrict__ v, float* __restrict__ ev) {
  __shared__ float in_s[8][160];
  __shared__ float vr[8][128];
  const int r0 = blockIdx.x * 8;
  const int tid = threadIdx.x;
  const int c = tid & 127, h = tid >> 7;
#pragma unroll
  for (int u = 0; u < 4; ++u) {
    int idx = u * 256 + tid;
    int rr = idx >> 7, k = idx & 127;
    in_s[rr][k] = pve[(r0 + rr) * 128 + k];
  }
  {
    int rr = tid >> 5, k = tid & 31;
    in_s[rr][128 + k] = v0[(r0 + rr) * 32 + k];
  }
  __syncthreads();
  float acc[4];
  const float bv = vb[c];
#pragma unroll
  for (int r = 0; r < 4; ++r) acc[r] = bv;
  for (int k4 = 0; k4 < 160; k4 += 4) {
    float w0 = vW[(k4 + 0) * 128 + c], w1 = vW[(k4 + 1) * 128 + c];
    float w2 = vW[(k4 + 2) * 128 + c], w3 = vW[(k4 + 3) * 128 + c];
#pragma unroll
    for (int r = 0; r < 4; ++r) {
      float4 x = *(const float4*)&in_s[h * 4 + r][k4];
      acc[r] += x.x * w0 + x.y * w1 + x.z * w2 + x.w * w3;
    }
  }
#pragma unroll
  for (int r = 0; r < 4; ++r) {
    float val = fmaxf(acc[r], 0.f);
    vr[h * 4 + r][c] = val;
    v[(r0 + h * 4 + r) * 128 + c] = val;
  }
  __syncthreads();
  float acc2[4];
  const float bv2 = evb[c];
#pragma unroll
  for (int r = 0; r < 4; ++r) acc2[r] = bv2;
  for (int k4 = 0; k4 < 128; k4 += 4) {
    float w0 = evW[(k4 + 0) * 128 + c], w1 = evW[(k4 + 1) * 128 + c];
    float w2 = evW[(k4 + 2) * 128 + c], w3 = evW[(k4 + 3) * 128 + c];
#pragma unroll
    for (int r = 0; r < 4; ++r) {
      float4 x = *(const float4*)&vr[h * 4 + r][k4];
      acc2[r] += x.x * w0 + x.y * w1 + x.z * w2 + x.w * w3;
    }
  }
#pragma unroll
  for (int r = 0; r < 4; ++r) ev[(r0 + h * 4 + r) * 128 + c] = acc2[r];
}

// ------------- inner edge pass: non-persistent 2048 blocks x 2 cols, lgkm barriers -------------
// e_t[b][j][i][c] transposed layout: block (b,j0) reads/writes one contiguous
// 32KB region. e += relu(e@W + eb + ev_i + ev_j); pve = pre-residual col sums.
// LAST: instead of e write-back, computes edot[b][j][i] = dot(e_new[b,i,j,:], eW3).
template <bool LAST>
__global__ __launch_bounds__(256) void k_edge_inner(bf16_t* __restrict__ e_ws,
    const bf16_t* __restrict__ Wt, const float* __restrict__ eb,
    const float* __restrict__ ev, float* __restrict__ pve,
    const float* __restrict__ eW3, float* __restrict__ edt) {
  __shared__ bf16_t As[2][64][136];   // [jc][i][c], +8 pad
  __shared__ float W3s[128];
  const int b = blockIdx.x >> 5, j0 = (blockIdx.x & 31) * 2;
  const int tid = threadIdx.x;
  const int lane = tid & 63, w = tid >> 6;
  const int quad = lane >> 4, l16 = lane & 15;
  bf16_t* ebase = &e_ws[((size_t)(b * 64 + j0) * 64) * 128];
  // stage 2 e columns: one contiguous 32KB stream
  int4 stg[8];
#pragma unroll
  for (int t = 0; t < 8; ++t) {
    int idx = tid + t * 256;
    stg[t] = *(const int4*)&ebase[idx * 8];
  }
  if (LAST) {
    if (tid < 128) W3s[tid] = eW3[tid];
  }
  // W A-frags in registers (L2-hot): A[m=c][k]
  bf16x8 wf[2][4];
#pragma unroll
  for (int nt = 0; nt < 2; ++nt)
#pragma unroll
    for (int ks = 0; ks < 4; ++ks)
      wf[nt][ks] = *(const bf16x8*)&Wt[(w * 32 + nt * 16 + l16) * 128 + ks * 32 + quad * 8];
  const int c0[2] = {w * 32 + quad * 4, w * 32 + 16 + quad * 4};
  // acc init = eb + ev_j + ev_i (pre-barrier loads)
  f32x4 acc[2][4][2];
  {
    f32x4 ebv[2], evj[2][2], evi[4][2];
#pragma unroll
    for (int nt = 0; nt < 2; ++nt) {
      ebv[nt] = *(const f32x4*)&eb[c0[nt]];
#pragma unroll
      for (int jc = 0; jc < 2; ++jc)
        evj[jc][nt] = *(const f32x4*)&ev[(b * 64 + j0 + jc) * 128 + c0[nt]];
#pragma unroll
      for (int mt = 0; mt < 4; ++mt)
        evi[mt][nt] = *(const f32x4*)&ev[(b * 64 + mt * 16 + l16) * 128 + c0[nt]];
    }
#pragma unroll
    for (int jc = 0; jc < 2; ++jc)
#pragma unroll
      for (int mt = 0; mt < 4; ++mt)
#pragma unroll
        for (int nt = 0; nt < 2; ++nt)
          acc[jc][mt][nt] = ebv[nt] + evj[jc][nt] + evi[mt][nt];
  }
#pragma unroll
  for (int t = 0; t < 8; ++t) {
    int idx = tid + t * 256;
    *(int4*)&As[idx >> 10][(idx >> 4) & 63][(idx & 15) * 8] = stg[t];
  }
  bar_lgkm();
  // MFMA: D[c][i] = sum_k Wt[c][k] * e[i][k]  (64 MFMA per block)
#pragma unroll
  for (int ks = 0; ks < 4; ++ks) {
    bf16x8 ef[2][4];
#pragma unroll
    for (int jc = 0; jc < 2; ++jc)
#pragma unroll
      for (int mt = 0; mt < 4; ++mt)
        ef[jc][mt] = *(const bf16x8*)&As[jc][mt * 16 + l16][ks * 32 + quad * 8];
#pragma unroll
    for (int jc = 0; jc < 2; ++jc)
#pragma unroll
      for (int mt = 0; mt < 4; ++mt)
#pragma unroll
        for (int nt = 0; nt < 2; ++nt)
          acc[jc][mt][nt] = __builtin_amdgcn_mfma_f32_16x16x32_bf16(wf[nt][ks], ef[jc][mt], acc[jc][mt][nt], 0, 0, 0);
  }
  bar_lgkm();  // all MFMA frag reads of As done (LDS-only dep)
  // epilogue: relu, pve, residual from LDS, packed b64 writes to own cells
#pragma unroll
  for (int jc = 0; jc < 2; ++jc) {
#pragma unroll
    for (int nt = 0; nt < 2; ++nt) {
      f32x4 ps = {0.f, 0.f, 0.f, 0.f};
#pragma unroll
      for (int mt = 0; mt < 4; ++mt) {
        const int i = mt * 16 + l16;
        bf16x4 eo = *(const bf16x4*)&As[jc][i][c0[nt]];
        bf16x4 outv;
#pragma unroll
        for (int r = 0; r < 4; ++r) {
          float vv = fmaxf(acc[jc][mt][nt][r], 0.f);
          ps[r] += vv;                            // pve is pre-residual
          outv[r] = (bf16_t)(vv + (float)eo[r]);  // residual
        }
        *(bf16x4*)&As[jc][i][c0[nt]] = outv;
      }
#pragma unroll
      for (int m = 1; m <= 8; m <<= 1) {  // reduce over i (l16 lanes)
#pragma unroll
        for (int r = 0; r < 4; ++r) ps[r] += __shfl_xor(ps[r], m);
      }
      if (l16 == 0) *(f32x4*)&pve[(b * 64 + j0 + jc) * 128 + c0[nt]] = ps;
    }
  }
  bar_lgkm();  // As fully updated (LDS-only dep)
  if (!LAST) {
    // contiguous 32KB write-back
#pragma unroll
    for (int t = 0; t < 8; ++t) {
      int idx = tid + t * 256;
      *(int4*)&ebase[idx * 8] =
          *(const int4*)&As[idx >> 10][(idx >> 4) & 63][(idx & 15) * 8];
    }
  } else {
    // edot[b][j][i] = dot(e_new[b,i,j,:], W3)
    const int i = tid >> 2, q = tid & 3;
#pragma unroll
    for (int jc = 0; jc < 2; ++jc) {
      float d = 0.f;
#pragma unroll
      for (int t = 0; t < 4; ++t) {
        bf16x8 x = *(const bf16x8*)&As[jc][i][q * 32 + t * 8];
#pragma unroll
        for (int u = 0; u < 8; ++u) d += (float)x[u] * W3s[q * 32 + t * 8 + u];
      }
      d += __shfl_xor(d, 1);
      d += __shfl_xor(d, 2);
      if (q == 0) edt[(b * 64 + j0 + jc) * 64 + i] = d;
    }
  }
}

// ------------- inner v pass: v = relu(concat(pve,v)@[256,128]+vb) + v; BN stats. 256 thr -------------
__global__ __launch_bounds__(256) void k_v_inner(const float* __restrict__ pve,
    float* __restrict__ v, const float* __restrict__ vW,
    const float* __restrict__ vb, float* __restrict__ stats) {
  __shared__ float in_s[8][256];
  __shared__ float outs[8][132];  // +4 pad
  __shared__ float part[16][2];
  const int r0 = blockIdx.x * 8;
  const int tid = threadIdx.x;
  const int c = tid & 127, h = tid >> 7;
#pragma unroll
  for (int u = 0; u < 4; ++u) {
    int idx = u * 256 + tid;
    int rr = idx >> 7, k = idx & 127;
    in_s[rr][k] = pve[(r0 + rr) * 128 + k];
    in_s[rr][128 + k] = v[(r0 + rr) * 128 + k];
  }
  __syncthreads();
  float acc[4];
  const float bv = vb[c];
#pragma unroll
  for (int r = 0; r < 4; ++r) acc[r] = bv;
  for (int k4 = 0; k4 < 256; k4 += 4) {
    float w0 = vW[(k4 + 0) * 128 + c], w1 = vW[(k4 + 1) * 128 + c];
    float w2 = vW[(k4 + 2) * 128 + c], w3 = vW[(k4 + 3) * 128 + c];
#pragma unroll
    for (int r = 0; r < 4; ++r) {
      float4 x = *(const float4*)&in_s[h * 4 + r][k4];
      acc[r] += x.x * w0 + x.y * w1 + x.z * w2 + x.w * w3;
    }
  }
#pragma unroll
  for (int r = 0; r < 4; ++r) {
    float val = fmaxf(acc[r], 0.f) + in_s[h * 4 + r][128 + c];  // relu + residual
    outs[h * 4 + r][c] = val;
    v[(r0 + h * 4 + r) * 128 + c] = val;
  }
  __syncthreads();
  if (tid < 16) {  // parallel BN-stat partial reduction
    int rr = tid >> 1, half = tid & 1;
    float s = 0.f, s2 = 0.f;
    for (int k = 0; k < 64; ++k) {
      float x = outs[rr][half * 64 + k];
      s += x; s2 += x * x;
    }
    part[tid][0] = s;
    part[tid][1] = s2;
  }
  __syncthreads();
  if (tid < 8) {
    int n = (r0 + tid) & 63;
    atomicAdd(&stats[n], part[tid * 2][0] + part[tid * 2 + 1][0]);
    atomicAdd(&stats[64 + n], part[tid * 2][1] + part[tid * 2 + 1][1]);
  }
}

// ------------- g3 final: per-b block. BN(v), ev3, out_e = edot+eb3+ev3_i+ev3_j,
// pve3 in LDS, out_v. One kernel, 64 blocks. -------------
__global__ __launch_bounds__(256) void k_g3(const float* __restrict__ vv,
    const float* __restrict__ stats3, const float* __restrict__ g,
    const float* __restrict__ bt, const float* __restrict__ evW3,
    const float* __restrict__ evb3, const float* __restrict__ eb3,
    const float* __restrict__ edt, const float* __restrict__ vW3,
    const float* __restrict__ vb3, float* __restrict__ out_v,
    float* __restrict__ out_e) {
  __shared__ float vbn[64][132];   // +4 pad
  __shared__ float edts[64][68];   // edt[b][j][i], +4 pad
  __shared__ float scs[64], shs[64];
  __shared__ float W3e[128];
  __shared__ float vWs[132];
  __shared__ float ev3s[64];
  __shared__ float pj[4][64];
  const int b = blockIdx.x, tid = threadIdx.x;
  if (tid < 64) {
    float mu = stats3[tid] * (1.f / 8192.f);
    float var = stats3[64 + tid] * (1.f / 8192.f) - mu * mu;
    float sc = rsqrtf(var + 128.f) * g[tid];
    scs[tid] = sc;
    shs[tid] = bt[tid] - mu * sc;
  }
  if (tid < 128) W3e[tid] = evW3[tid];
  if (tid < 129) vWs[tid] = vW3[tid];
  __syncthreads();
#pragma unroll
  for (int t = 0; t < 8; ++t) {  // stage BN(v[b])
    int idx = t * 1024 + tid * 4;
    int row = idx >> 7, cc = idx & 127;
    f32x4 x = *(const f32x4*)&vv[(b * 64 + row) * 128 + cc];
    *(f32x4*)&vbn[row][cc] = x * scs[row] + shs[row];
  }
#pragma unroll
  for (int t = 0; t < 4; ++t) {  // stage edot[b]
    int idx = t * 1024 + tid * 4;
    int j = idx >> 6, i = idx & 63;
    *(f32x4*)&edts[j][i] = *(const f32x4*)&edt[(b * 64 + j) * 64 + i];
  }
  __syncthreads();
  {  // ev3s[i] = dot(vbn[i], W3e) + evb3
    int i = tid >> 2, q = tid & 3;
    float d = 0.f;
#pragma unroll
    for (int u = 0; u < 32; ++u) d += vbn[i][q * 32 + u] * W3e[q * 32 + u];
    d += __shfl_xor(d, 1);
    d += __shfl_xor(d, 2);
    if (q == 0) ev3s[i] = d + evb3[0];
  }
  __syncthreads();
  {  // out_e + per-j partial sums
    int q = tid >> 6, j = tid & 63;
    float s = 0.f;
    const float e3 = eb3[0];
    const float evj = ev3s[j];
#pragma unroll
    for (int r = 0; r < 16; ++r) {
      int i = q * 16 + r;
      float val = edts[j][i] + e3 + ev3s[i] + evj;
      out_e[(b * 64 + i) * 64 + j] = val;
      s += val;
    }
    pj[q][j] = s;
  }
  __syncthreads();
  {  // out_v[b,n] = pve3*vW[0] + dot(vbn[n], vW[1:129]) + vb
    int n = tid >> 2, q = tid & 3;
    float d = 0.f;
#pragma unroll
    for (int u = 0; u < 32; ++u) d += vbn[n][q * 32 + u] * vWs[1 + q * 32 + u];
    d += __shfl_xor(d, 1);
    d += __shfl_xor(d, 2);
    if (q == 0) {
      float p3 = pj[0][n] + pj[1][n] + pj[2][n] + pj[3][n];
      out_v[b * 64 + n] = d + p3 * vWs[0] + vb3[0];
    }
  }
}

extern "C" void kernel_launch(void* const* d_in, const int* in_sizes, int n_in,
                              void* d_out, int out_size, void* d_ws, size_t ws_size,
                              hipStream_t stream) {
  const float* in_v    = (const float*)d_in[0];
  const float* in_e    = (const float*)d_in[1];
  const float* bn_in_g = (const float*)d_in[2];
  const float* bn_in_b = (const float*)d_in[3];
  const float* g1_evW  = (const float*)d_in[4];
  const float* g1_evb  = (const float*)d_in[5];
  const float* g1_eW   = (const float*)d_in[6];
  const float* g1_eb   = (const float*)d_in[7];
  const float* g1_vW   = (const float*)d_in[8];
  const float* g1_vb   = (const float*)d_in[9];
  const float* inn_evW = (const float*)d_in[10];
  const float* inn_evb = (const float*)d_in[11];
  const float* inn_eW  = (const float*)d_in[12];
  const float* inn_eb  = (const float*)d_in[13];
  const float* inn_vW  = (const float*)d_in[14];
  const float* inn_vb  = (const float*)d_in[15];
  const float* bn_g    = (const float*)d_in[16];
  const float* bn_b    = (const float*)d_in[17];
  const float* g3_evW  = (const float*)d_in[18];
  const float* g3_evb  = (const float*)d_in[19];
  const float* g3_eW   = (const float*)d_in[20];
  const float* g3_eb   = (const float*)d_in[21];
  const float* g3_vW   = (const float*)d_in[22];
  const float* g3_vb   = (const float*)d_in[23];

  char* ws = (char*)d_ws;
  bf16_t* e_ws = (bf16_t*)(ws);                       // 64MB : e_t[b][j][i][c] bf16
  float* v     = (float*)(ws + 67108864);             // 2MB
  float* ev    = (float*)(ws + 69206016);             // 2MB
  float* pve   = (float*)(ws + 71303168);             // 2MB
  float* v0    = (float*)(ws + 73400320);             // 512KB
  bf16_t* Wt   = (bf16_t*)(ws + 73924608);            // 128KB
  float* edt   = (float*)(ws + 74055680);             // 1MB : edot[b][j][i]
  float* stats = (float*)(ws + 75104256);             // 2KB (4 layers x 128 f32)

  float* out_v = (float*)d_out;          // [B,N,1] = 4096
  float* out_e = (float*)d_out + 4096;   // [B,N,N,1] = 262144

  k_prep<<<265, 256, 0, stream>>>(in_v, bn_in_g, bn_in_b, inn_eW, v0, Wt, stats);

  // ---- g1 ----
  k_ev<32><<<512, 256, 0, stream>>>(v0, g1_evW, g1_evb, ev);
  k_edge_g1<<<2048, 256, 0, stream>>>(in_e, g1_eW, g1_eb, ev, e_ws, pve);
  k_vg1_ev<<<512, 256, 0, stream>>>(pve, v0, g1_vW, g1_vb, inn_evW, inn_evb, v, ev);

  // ---- inner layers ----
  for (int l = 0; l < 4; ++l) {
    if (l > 0)
      k_evbn<<<512, 256, 0, stream>>>(v, stats + (l - 1) * 128, bn_g + (l - 1) * 64,
                                      bn_b + (l - 1) * 64, inn_evW + l * 16384,
                                      inn_evb + l * 128, ev);
    if (l < 3)
      k_edge_inner<false><<<2048, 256, 0, stream>>>(e_ws, Wt + l * 16384,
          inn_eb + l * 128, ev, pve, g3_eW, edt);
    else
      k_edge_inner<true><<<2048, 256, 0, stream>>>(e_ws, Wt + l * 16384,
          inn_eb + l * 128, ev, pve, g3_eW, edt);
    k_v_inner<<<512, 256, 0, stream>>>(pve, v, inn_vW + l * 32768, inn_vb + l * 128,
                                       stats + l * 128);
  }

  // ---- g3 final (BN of layer 3 on the fly; pve3 in-block) ----
  k_g3<<<64, 256, 0, stream>>>(v, stats + 384, bn_g + 192, bn_b + 192,
                               g3_evW, g3_evb, g3_eb, edt, g3_vW, g3_vb,
                               out_v, out_e);
}